// Round 3
// baseline (1138.119 us; speedup 1.0000x reference)
//
#include <hip/hip_runtime.h>
#include <hip/hip_bf16.h>

// BranchingQNetwork fused forward for MI355X (gfx950).
// B=32, N=2048, OBS=256, HID=128, n1=n2=8.

typedef __attribute__((ext_vector_type(4))) float f32x4;
typedef __attribute__((ext_vector_type(8))) short bf16x8;
typedef __attribute__((ext_vector_type(4))) unsigned int u32x4;

#define LOG2E 1.44269504088896340736f
#define NEGC 9.0e15f

static __device__ __forceinline__ unsigned short f2bf(float f) {
  unsigned int x = __builtin_bit_cast(unsigned int, f);
  unsigned int r = (x + 0x7fffu + ((x >> 16) & 1u)) >> 16;   // RNE
  return (unsigned short)r;
}
static __device__ __forceinline__ float bf2f(unsigned short u) {
  return __builtin_bit_cast(float, ((unsigned int)u) << 16);
}
static __device__ __forceinline__ unsigned int pack2bf(float lo, float hi) {
  return (unsigned int)f2bf(lo) | ((unsigned int)f2bf(hi) << 16);
}
static __device__ __forceinline__ f32x4 mfma16(bf16x8 a, bf16x8 b, f32x4 c) {
  return __builtin_amdgcn_mfma_f32_16x16x32_bf16(a, b, c, 0, 0, 0);
}

// ---------------------------------------------------------------------------
// Kernel 0: weight prep. WT (384 cols = [q|k|v]) transposed to [col][256] bf16
// hi/lo split; WoutT transposed to [col][128] bf16.
// ---------------------------------------------------------------------------
__global__ void prep_kernel(const float* __restrict__ Wv, const float* __restrict__ Wk,
                            const float* __restrict__ Wq, const float* __restrict__ Wout,
                            unsigned short* __restrict__ WT_hi, unsigned short* __restrict__ WT_lo,
                            unsigned short* __restrict__ WoutT) {
  int idx = blockIdx.x * 256 + threadIdx.x;
  if (idx < 384 * 256) {
    int j = idx >> 8;      // output col 0..383  (0..127=q, 128..255=k, 256..383=v)
    int c = idx & 255;     // k index
    const float* W = (j < 128) ? Wq : (j < 256) ? Wk : Wv;
    float w = W[c * 128 + (j & 127)];
    unsigned short hi = f2bf(w);
    WT_hi[idx] = hi;
    WT_lo[idx] = f2bf(w - bf2f(hi));
  } else {
    int i2 = idx - 384 * 256;
    if (i2 < 128 * 128) {
      int j = i2 >> 7, c = i2 & 127;
      WoutT[i2] = f2bf(Wout[c * 128 + j]);
    }
  }
}

// ---------------------------------------------------------------------------
// Kernel 1: fused QKV projection. 64 rows/block, 4 waves x 16 rows x 384 cols.
// 3-pass hi/lo split MFMA, relu+bias; q -> bf16, k -> hi/lo bf16,
// v -> staged in LDS and written TRANSPOSED as vT[b][h][n].
// ---------------------------------------------------------------------------
__global__ __launch_bounds__(256) void proj_kernel(
    const float* __restrict__ x,
    const unsigned short* __restrict__ WT_hi, const unsigned short* __restrict__ WT_lo,
    const float* __restrict__ bq, const float* __restrict__ bk, const float* __restrict__ bv,
    unsigned short* __restrict__ q_bf, unsigned short* __restrict__ k_hi,
    unsigned short* __restrict__ k_lo, unsigned short* __restrict__ vT) {
  __shared__ unsigned short vbuf[64][132];
  const int lane = threadIdx.x & 63, wid = threadIdx.x >> 6;
  const int qq = lane >> 4, hh = lane & 15;
  const long rowA = (long)blockIdx.x * 64 + wid * 16 + hh;  // A-frag row
  const f32x4 zero4 = {0.f, 0.f, 0.f, 0.f};
  f32x4 acc[24];
#pragma unroll
  for (int t = 0; t < 24; ++t) acc[t] = zero4;

  for (int kc = 0; kc < 8; ++kc) {
    const float* xp = x + rowA * 256 + kc * 32 + qq * 8;
    f32x4 x0 = *(const f32x4*)xp;
    f32x4 x1 = *(const f32x4*)(xp + 4);
    bf16x8 ah, al;
#pragma unroll
    for (int j = 0; j < 8; ++j) {
      float f = (j < 4) ? x0[j] : x1[j - 4];
      unsigned short h = f2bf(f);
      ah[j] = (short)h;
      al[j] = (short)f2bf(f - bf2f(h));
    }
#pragma unroll
    for (int t = 0; t < 24; ++t) {
      const unsigned short* wp = WT_hi + (t * 16 + hh) * 256 + kc * 32 + qq * 8;
      const unsigned short* wl = WT_lo + (t * 16 + hh) * 256 + kc * 32 + qq * 8;
      bf16x8 bh = *(const bf16x8*)wp;
      bf16x8 bl = *(const bf16x8*)wl;
      acc[t] = mfma16(ah, bh, acc[t]);
      acc[t] = mfma16(al, bh, acc[t]);
      acc[t] = mfma16(ah, bl, acc[t]);
    }
  }
  const long rowC = (long)blockIdx.x * 64 + wid * 16 + qq * 4;
  const int rowL = wid * 16 + qq * 4;
#pragma unroll
  for (int t = 0; t < 24; ++t) {
    const int col = t * 16 + hh;
    const int sec = t >> 3;        // 0=q 1=k 2=v (uniform per t)
    const int j = col & 127;
    const float bias = (sec == 0) ? bq[j] : (sec == 1) ? bk[j] : bv[j];
#pragma unroll
    for (int r = 0; r < 4; ++r) {
      float val = fmaxf(acc[t][r] + bias, 0.f);
      long o = (rowC + r) * 128 + j;
      if (sec == 0) {
        q_bf[o] = f2bf(val);
      } else if (sec == 1) {
        unsigned short h = f2bf(val);
        k_hi[o] = h;
        k_lo[o] = f2bf(val - bf2f(h));
      } else {
        vbuf[rowL + r][j] = f2bf(val);
      }
    }
  }
  __syncthreads();
  // cooperative transposed write: vT[(b*128 + h)*2048 + n]
  {
    const int tid = threadIdx.x;
    const int j = tid >> 1;          // h col 0..127
    const int half = tid & 1;        // n half (32 each)
    const long nbase = (long)blockIdx.x * 64;
    const int bb = (int)(nbase >> 11);
    const int noff = (int)(nbase & 2047);
    unsigned short* op = vT + ((long)bb * 128 + j) * 2048 + noff + half * 32;
#pragma unroll
    for (int g = 0; g < 4; ++g) {
      u32x4 w;
#pragma unroll
      for (int d = 0; d < 4; ++d) {
        int i = g * 8 + d * 2;
        w[d] = (unsigned int)vbuf[half * 32 + i][j] |
               ((unsigned int)vbuf[half * 32 + i + 1][j] << 16);
      }
      *(u32x4*)(op + g * 8) = w;
    }
  }
}

// ---------------------------------------------------------------------------
// Kernel 2: flash attention, zero LDS, latency-optimized.
// 16 q-rows per wave (4096 waves total -> 16 waves/CU at 4 blocks/CU).
// XCD-aware batch clustering: b = (orig&7)*4 + ((orig>>3)&3), nb = orig>>5,
// so each XCD's blocks serve only 4 batches and sweep K/V tiles in lockstep
// (K/V becomes XCD-L2-resident).
// Swapped QK^T: S^T = K·Q^T (C row=kv, col=q) -> mask loads are dwordx4,
// softmax factors are per-lane scalars. PV: O^T = V^T·P from pre-transposed
// vT. P redistribution via in-register shfl. 2-pass hi/lo K for precision.
// ---------------------------------------------------------------------------
__global__ __launch_bounds__(256, 4) void attn_kernel(
    const unsigned short* __restrict__ q_bf, const unsigned short* __restrict__ k_hi,
    const unsigned short* __restrict__ k_lo, const unsigned short* __restrict__ vT,
    const float* __restrict__ mask, unsigned short* __restrict__ out_att) {
  const int lane = threadIdx.x & 63, wid = threadIdx.x >> 6;
  const int qq = lane >> 4, hh = lane & 15;
  const int orig = blockIdx.x;
  const int b = ((orig & 7) << 2) | ((orig >> 3) & 3);
  const int nb = orig >> 5;
  const long qbase = (long)b * 2048 + nb * 64 + wid * 16;
  const f32x4 zero4 = {0.f, 0.f, 0.f, 0.f};

  // hoisted Q fragments (B-operand): Q[q = hh][h = kc*32+qq*8+j]
  bf16x8 qh[4];
#pragma unroll
  for (int kc = 0; kc < 4; ++kc)
    qh[kc] = *(const bf16x8*)(q_bf + (qbase + hh) * 128 + kc * 32 + qq * 8);

  const float* mrow = mask + (qbase + hh) * 2048;
  const unsigned short* khl = k_hi + (long)b * 262144 + hh * 128 + qq * 8;
  const unsigned short* kll = k_lo + (long)b * 262144 + hh * 128 + qq * 8;
  const unsigned short* vl  = vT   + ((long)b * 128 + hh) * 2048 + qq * 8;

  f32x4 o_acc[8];
#pragma unroll
  for (int ht = 0; ht < 8; ++ht) o_acc[ht] = zero4;
  float m_run = -3.0e38f;
  float l_run = 0.f;

  // prefetch mask tile 0 (C-frag layout: [kv = m*16+qq*4+r][q = hh])
  f32x4 mk[4];
#pragma unroll
  for (int m = 0; m < 4; ++m)
    mk[m] = *(const f32x4*)(mrow + m * 16 + qq * 4);

  const int src0 = (((qq << 1)) & 3) * 16 + hh;
  const int src1 = (((qq << 1) + 1) & 3) * 16 + hh;
  const bool hiq = qq >= 2;

  for (int t = 0; t < 32; ++t) {
    const int koff = t * 8192;   // t*64 rows * 128

    // S^T = K·Q^T (2-pass hi/lo K)
    f32x4 s[4];
#pragma unroll
    for (int m = 0; m < 4; ++m) s[m] = zero4;
#pragma unroll
    for (int m = 0; m < 4; ++m) {
      bf16x8 khf[4], klf[4];
#pragma unroll
      for (int kc = 0; kc < 4; ++kc) {
        khf[kc] = *(const bf16x8*)(khl + koff + m * 2048 + kc * 32);
        klf[kc] = *(const bf16x8*)(kll + koff + m * 2048 + kc * 32);
      }
#pragma unroll
      for (int kc = 0; kc < 4; ++kc) {
        s[m] = mfma16(khf[kc], qh[kc], s[m]);
        s[m] = mfma16(klf[kc], qh[kc], s[m]);
      }
    }

    // apply mask (consumes mk), then prefetch next tile's mask
#pragma unroll
    for (int m = 0; m < 4; ++m) {
      f32x4 mv = mk[m];
      s[m] = mv * s[m] - NEGC * (1.0f - mv);
    }
    if (t + 1 < 32) {
      const int mo = (t + 1) * 64;
#pragma unroll
      for (int m = 0; m < 4; ++m)
        mk[m] = *(const f32x4*)(mrow + mo + m * 16 + qq * 4);
    }

    // fp32 online softmax (per q col = hh; per-lane scalars)
    float mx = s[0][0];
#pragma unroll
    for (int m = 0; m < 4; ++m)
#pragma unroll
      for (int r = 0; r < 4; ++r) mx = fmaxf(mx, s[m][r]);
    mx = fmaxf(mx, __shfl_xor(mx, 16, 64));
    mx = fmaxf(mx, __shfl_xor(mx, 32, 64));
    float mnew = fmaxf(m_run, mx);
    float sc = exp2f((m_run - mnew) * LOG2E);
    m_run = mnew;
    float ps = 0.f;
#pragma unroll
    for (int m = 0; m < 4; ++m)
#pragma unroll
      for (int r = 0; r < 4; ++r) {
        float p = exp2f((s[m][r] - mnew) * LOG2E);
        s[m][r] = p;
        ps += p;
      }
    ps += __shfl_xor(ps, 16, 64);
    ps += __shfl_xor(ps, 32, 64);
    l_run = l_run * sc + ps;
#pragma unroll
    for (int ht = 0; ht < 8; ++ht) o_acc[ht] *= sc;

    unsigned int pk[4][2];
#pragma unroll
    for (int m = 0; m < 4; ++m) {
      pk[m][0] = pack2bf(s[m][0], s[m][1]);
      pk[m][1] = pack2bf(s[m][2], s[m][3]);
    }

    // redistribute P (C layout) -> B-frag layout via shfl
    bf16x8 pb[2];
#pragma unroll
    for (int c = 0; c < 2; ++c) {
      unsigned int a0 = (unsigned int)__shfl((int)pk[2 * c][0], src0, 64);
      unsigned int a1 = (unsigned int)__shfl((int)pk[2 * c][1], src0, 64);
      unsigned int a2 = (unsigned int)__shfl((int)pk[2 * c][0], src1, 64);
      unsigned int a3 = (unsigned int)__shfl((int)pk[2 * c][1], src1, 64);
      unsigned int b0 = (unsigned int)__shfl((int)pk[2 * c + 1][0], src0, 64);
      unsigned int b1 = (unsigned int)__shfl((int)pk[2 * c + 1][1], src0, 64);
      unsigned int b2 = (unsigned int)__shfl((int)pk[2 * c + 1][0], src1, 64);
      unsigned int b3 = (unsigned int)__shfl((int)pk[2 * c + 1][1], src1, 64);
      u32x4 w;
      w[0] = hiq ? b0 : a0;
      w[1] = hiq ? b1 : a1;
      w[2] = hiq ? b2 : a2;
      w[3] = hiq ? b3 : a3;
      pb[c] = __builtin_bit_cast(bf16x8, w);
    }

    // O^T += V^T · P
#pragma unroll
    for (int ht = 0; ht < 8; ++ht)
#pragma unroll
      for (int c = 0; c < 2; ++c) {
        bf16x8 vf = *(const bf16x8*)(vl + ht * 32768 + t * 64 + c * 32);
        o_acc[ht] = mfma16(vf, pb[c], o_acc[ht]);
      }
  }

  // epilogue: normalize, store bf16. O^T frag: row h = ht*16+qq*4+r, col q = hh.
  {
    float inv = 1.0f / l_run;
    const long row = qbase + hh;
#pragma unroll
    for (int ht = 0; ht < 8; ++ht) {
      f32x4 o = o_acc[ht];
      uint2 w;
      w.x = pack2bf(o[0] * inv, o[1] * inv);
      w.y = pack2bf(o[2] * inv, o[3] * inv);
      *(uint2*)(out_att + row * 128 + ht * 16 + qq * 4) = w;
    }
  }
}

// ---------------------------------------------------------------------------
// Kernel 3: out = relu(out_att @ Wout + bout) fused with the three heads.
// ---------------------------------------------------------------------------
__global__ __launch_bounds__(256) void wout_heads_kernel(
    const unsigned short* __restrict__ out_att, const unsigned short* __restrict__ WoutT,
    const float* __restrict__ bout,
    const float* __restrict__ Wval, const float* __restrict__ bval,
    const float* __restrict__ Wadv1, const float* __restrict__ badv1,
    const float* __restrict__ Wadv2, const float* __restrict__ badv2,
    float* __restrict__ value, float* __restrict__ adv1, float* __restrict__ adv2) {
  const int lane = threadIdx.x & 63, wid = threadIdx.x >> 6;
  const int qq = lane >> 4, hh = lane & 15;
  const long rowA = (long)blockIdx.x * 64 + wid * 16 + hh;
  const f32x4 zero4 = {0.f, 0.f, 0.f, 0.f};
  f32x4 acc[8];
#pragma unroll
  for (int t = 0; t < 8; ++t) acc[t] = zero4;
#pragma unroll
  for (int kc = 0; kc < 4; ++kc) {
    bf16x8 af = *(const bf16x8*)(out_att + rowA * 128 + kc * 32 + qq * 8);
#pragma unroll
    for (int t = 0; t < 8; ++t) {
      bf16x8 bf = *(const bf16x8*)(WoutT + (t * 16 + hh) * 128 + kc * 32 + qq * 8);
      acc[t] = mfma16(af, bf, acc[t]);
    }
  }
  float pv[4] = {0.f, 0.f, 0.f, 0.f};
  float pa1[4][8], pa2[4][8];
#pragma unroll
  for (int r = 0; r < 4; ++r)
#pragma unroll
    for (int j = 0; j < 8; ++j) { pa1[r][j] = 0.f; pa2[r][j] = 0.f; }
#pragma unroll
  for (int t = 0; t < 8; ++t) {
    const int col = t * 16 + hh;
    const float bo = bout[col];
    const float wv = Wval[col];
    const f32x4 w1a = *(const f32x4*)(Wadv1 + col * 8);
    const f32x4 w1b = *(const f32x4*)(Wadv1 + col * 8 + 4);
    const f32x4 w2a = *(const f32x4*)(Wadv2 + col * 8);
    const f32x4 w2b = *(const f32x4*)(Wadv2 + col * 8 + 4);
#pragma unroll
    for (int r = 0; r < 4; ++r) {
      float h = fmaxf(acc[t][r] + bo, 0.f);
      pv[r] += h * wv;
#pragma unroll
      for (int j = 0; j < 4; ++j) {
        pa1[r][j]     += h * w1a[j];
        pa1[r][4 + j] += h * w1b[j];
        pa2[r][j]     += h * w2a[j];
        pa2[r][4 + j] += h * w2b[j];
      }
    }
  }
#pragma unroll
  for (int r = 0; r < 4; ++r) {
#pragma unroll
    for (int s = 1; s < 16; s <<= 1) {
      pv[r] += __shfl_xor(pv[r], s, 64);
#pragma unroll
      for (int j = 0; j < 8; ++j) {
        pa1[r][j] += __shfl_xor(pa1[r][j], s, 64);
        pa2[r][j] += __shfl_xor(pa2[r][j], s, 64);
      }
    }
  }
  if (hh == 0) {
    const float bv0 = bval[0];
#pragma unroll
    for (int r = 0; r < 4; ++r) {
      const long row = (long)blockIdx.x * 64 + wid * 16 + qq * 4 + r;
      value[row] = pv[r] + bv0;
#pragma unroll
      for (int j = 0; j < 8; ++j) {
        adv1[row * 8 + j] = pa1[r][j] + badv1[j];
        adv2[row * 8 + j] = pa2[r][j] + badv2[j];
      }
    }
  }
}

// ---------------------------------------------------------------------------
// Kernel 4: per-batch column sums of adv1/adv2 over N (deterministic tree).
// ---------------------------------------------------------------------------
__global__ __launch_bounds__(256) void sums_kernel(const float* __restrict__ adv1,
                                                   const float* __restrict__ adv2,
                                                   float* __restrict__ sums) {
  const int b = blockIdx.x, tid = threadIdx.x;
  __shared__ float red[4][16];
  float p[16];
#pragma unroll
  for (int j = 0; j < 16; ++j) p[j] = 0.f;
  for (int n = tid; n < 2048; n += 256) {
    const long row = (long)b * 2048 + n;
    const f32x4 a1a = *(const f32x4*)(adv1 + row * 8);
    const f32x4 a1b = *(const f32x4*)(adv1 + row * 8 + 4);
    const f32x4 a2a = *(const f32x4*)(adv2 + row * 8);
    const f32x4 a2b = *(const f32x4*)(adv2 + row * 8 + 4);
#pragma unroll
    for (int j = 0; j < 4; ++j) {
      p[j] += a1a[j]; p[4 + j] += a1b[j];
      p[8 + j] += a2a[j]; p[12 + j] += a2b[j];
    }
  }
#pragma unroll
  for (int s = 1; s < 64; s <<= 1)
#pragma unroll
    for (int j = 0; j < 16; ++j) p[j] += __shfl_xor(p[j], s, 64);
  const int wid = tid >> 6;
  if ((tid & 63) == 0)
#pragma unroll
    for (int j = 0; j < 16; ++j) red[wid][j] = p[j];
  __syncthreads();
  if (tid < 16)
    sums[b * 16 + tid] = red[0][tid] + red[1][tid] + red[2][tid] + red[3][tid];
}

// ---------------------------------------------------------------------------
// Kernel 5: q1/q2 = value + adv - mean(adv). Output: [q1 | q2] fp32 flat.
// ---------------------------------------------------------------------------
__global__ void combine_kernel(const float* __restrict__ value, const float* __restrict__ adv1,
                               const float* __restrict__ adv2, const float* __restrict__ sums,
                               float* __restrict__ out) {
  const int idx = blockIdx.x * 256 + threadIdx.x;   // 0 .. 1048575
  const int half = 524288;
  const int which = (idx >= half) ? 1 : 0;
  const int rem = idx - which * half;
  const int b = rem >> 14;
  const int r2 = rem & 16383;
  const int n = r2 >> 3, j = r2 & 7;
  const long row = (long)b * 2048 + n;
  const float* adv = which ? adv2 : adv1;
  const float mean = sums[b * 16 + which * 8 + j] * (1.0f / 2048.0f);
  out[idx] = value[row] + adv[row * 8 + j] - mean;
}

// ---------------------------------------------------------------------------
extern "C" void kernel_launch(void* const* d_in, const int* in_sizes, int n_in,
                              void* d_out, int out_size, void* d_ws, size_t ws_size,
                              hipStream_t stream) {
  const float* x     = (const float*)d_in[0];
  const float* mask  = (const float*)d_in[1];
  const float* Wv    = (const float*)d_in[2];
  const float* bv    = (const float*)d_in[3];
  const float* Wk    = (const float*)d_in[4];
  const float* bk    = (const float*)d_in[5];
  const float* Wq    = (const float*)d_in[6];
  const float* bq    = (const float*)d_in[7];
  const float* Wout  = (const float*)d_in[8];
  const float* bout  = (const float*)d_in[9];
  const float* Wval  = (const float*)d_in[10];
  const float* bval  = (const float*)d_in[11];
  const float* Wadv1 = (const float*)d_in[12];
  const float* badv1 = (const float*)d_in[13];
  const float* Wadv2 = (const float*)d_in[14];
  const float* badv2 = (const float*)d_in[15];
  float* out = (float*)d_out;
  char* ws = (char*)d_ws;

  // workspace layout (bytes)
  unsigned short* q_bf   = (unsigned short*)(ws + 0);
  unsigned short* k_hi   = (unsigned short*)(ws + 16777216);
  unsigned short* k_lo   = (unsigned short*)(ws + 33554432);
  unsigned short* vT     = (unsigned short*)(ws + 50331648);
  unsigned short* out_at = (unsigned short*)(ws + 67108864);
  float* value = (float*)(ws + 83886080);
  float* adv1  = (float*)(ws + 84148224);
  float* adv2  = (float*)(ws + 86245376);
  float* sums  = (float*)(ws + 88342528);
  unsigned short* WT_hi = (unsigned short*)(ws + 88344576);
  unsigned short* WT_lo = (unsigned short*)(ws + 88541184);
  unsigned short* WoutT = (unsigned short*)(ws + 88737792);

  prep_kernel<<<448, 256, 0, stream>>>(Wv, Wk, Wq, Wout, WT_hi, WT_lo, WoutT);
  proj_kernel<<<1024, 256, 0, stream>>>(x, WT_hi, WT_lo, bq, bk, bv,
                                        q_bf, k_hi, k_lo, vT);
  attn_kernel<<<1024, 256, 0, stream>>>(q_bf, k_hi, k_lo, vT, mask, out_at);
  wout_heads_kernel<<<1024, 256, 0, stream>>>(out_at, WoutT, bout, Wval, bval,
                                              Wadv1, badv1, Wadv2, badv2,
                                              value, adv1, adv2);
  sums_kernel<<<32, 256, 0, stream>>>(adv1, adv2, sums);
  combine_kernel<<<4096, 256, 0, stream>>>(value, adv1, adv2, sums, out);
}

// Round 4
// 741.796 us; speedup vs baseline: 1.5343x; 1.5343x over previous
//
#include <hip/hip_runtime.h>
#include <hip/hip_bf16.h>

// BranchingQNetwork fused forward for MI355X (gfx950).
// B=32, N=2048, OBS=256, HID=128, n1=n2=8.

typedef __attribute__((ext_vector_type(4))) float f32x4;
typedef __attribute__((ext_vector_type(8))) short bf16x8;
typedef __attribute__((ext_vector_type(4))) unsigned int u32x4;

#define LOG2E 1.44269504088896340736f
#define NEGC 9.0e15f

static __device__ __forceinline__ unsigned short f2bf(float f) {
  unsigned int x = __builtin_bit_cast(unsigned int, f);
  unsigned int r = (x + 0x7fffu + ((x >> 16) & 1u)) >> 16;   // RNE
  return (unsigned short)r;
}
static __device__ __forceinline__ float bf2f(unsigned short u) {
  return __builtin_bit_cast(float, ((unsigned int)u) << 16);
}
static __device__ __forceinline__ unsigned int pack2bf(float lo, float hi) {
  return (unsigned int)f2bf(lo) | ((unsigned int)f2bf(hi) << 16);
}
static __device__ __forceinline__ f32x4 mfma16(bf16x8 a, bf16x8 b, f32x4 c) {
  return __builtin_amdgcn_mfma_f32_16x16x32_bf16(a, b, c, 0, 0, 0);
}

// ---------------------------------------------------------------------------
// Kernel P: mask prepack. mask fp32 [32][2048][2048] -> bitmask u64
// bits[row][t] covers kv = t*64..t*64+63 for global q-row `row`.
// Wave reads 64 consecutive floats (256B/instr, streaming) -> __ballot -> u64.
// 537 MB -> 16.8 MB (32x traffic cut); kills the 8KB-stride DRAM thrash.
// ---------------------------------------------------------------------------
__global__ __launch_bounds__(256) void prepack_kernel(const float* __restrict__ mask,
                                                      unsigned long long* __restrict__ bits) {
  const int lane = threadIdx.x & 63;
  const int gwave = (blockIdx.x << 2) | (threadIdx.x >> 6);  // 8192 waves
  // each wave packs 8 rows
  for (int r = 0; r < 8; ++r) {
    const long row = (long)gwave * 8 + r;
    const float* mp = mask + row * 2048 + lane;
    unsigned long long* op = bits + row * 32;
#pragma unroll
    for (int g = 0; g < 8; ++g) {
      float f0 = mp[(g * 4 + 0) * 64];
      float f1 = mp[(g * 4 + 1) * 64];
      float f2 = mp[(g * 4 + 2) * 64];
      float f3 = mp[(g * 4 + 3) * 64];
      unsigned long long b0 = __ballot(f0 != 0.0f);
      unsigned long long b1 = __ballot(f1 != 0.0f);
      unsigned long long b2 = __ballot(f2 != 0.0f);
      unsigned long long b3 = __ballot(f3 != 0.0f);
      if (lane == 0) {
        ulonglong2 w0 = {b0, b1};
        ulonglong2 w1 = {b2, b3};
        *(ulonglong2*)(op + g * 4) = w0;
        *(ulonglong2*)(op + g * 4 + 2) = w1;
      }
    }
  }
}

// ---------------------------------------------------------------------------
// Kernel 0: weight prep. WT (384 cols = [q|k|v]) transposed to [col][256] bf16
// hi/lo split; WoutT transposed to [col][128] bf16.
// ---------------------------------------------------------------------------
__global__ void prep_kernel(const float* __restrict__ Wv, const float* __restrict__ Wk,
                            const float* __restrict__ Wq, const float* __restrict__ Wout,
                            unsigned short* __restrict__ WT_hi, unsigned short* __restrict__ WT_lo,
                            unsigned short* __restrict__ WoutT) {
  int idx = blockIdx.x * 256 + threadIdx.x;
  if (idx < 384 * 256) {
    int j = idx >> 8;      // output col 0..383  (0..127=q, 128..255=k, 256..383=v)
    int c = idx & 255;     // k index
    const float* W = (j < 128) ? Wq : (j < 256) ? Wk : Wv;
    float w = W[c * 128 + (j & 127)];
    unsigned short hi = f2bf(w);
    WT_hi[idx] = hi;
    WT_lo[idx] = f2bf(w - bf2f(hi));
  } else {
    int i2 = idx - 384 * 256;
    if (i2 < 128 * 128) {
      int j = i2 >> 7, c = i2 & 127;
      WoutT[i2] = f2bf(Wout[c * 128 + j]);
    }
  }
}

// ---------------------------------------------------------------------------
// Kernel 1: fused QKV projection. 64 rows/block, 4 waves x 16 rows x 384 cols.
// 3-pass hi/lo split MFMA, relu+bias; q -> bf16, k -> hi/lo bf16,
// v -> staged in LDS and written TRANSPOSED as vT[b][h][n].
// ---------------------------------------------------------------------------
__global__ __launch_bounds__(256) void proj_kernel(
    const float* __restrict__ x,
    const unsigned short* __restrict__ WT_hi, const unsigned short* __restrict__ WT_lo,
    const float* __restrict__ bq, const float* __restrict__ bk, const float* __restrict__ bv,
    unsigned short* __restrict__ q_bf, unsigned short* __restrict__ k_hi,
    unsigned short* __restrict__ k_lo, unsigned short* __restrict__ vT) {
  __shared__ unsigned short vbuf[64][132];
  const int lane = threadIdx.x & 63, wid = threadIdx.x >> 6;
  const int qq = lane >> 4, hh = lane & 15;
  const long rowA = (long)blockIdx.x * 64 + wid * 16 + hh;  // A-frag row
  const f32x4 zero4 = {0.f, 0.f, 0.f, 0.f};
  f32x4 acc[24];
#pragma unroll
  for (int t = 0; t < 24; ++t) acc[t] = zero4;

  for (int kc = 0; kc < 8; ++kc) {
    const float* xp = x + rowA * 256 + kc * 32 + qq * 8;
    f32x4 x0 = *(const f32x4*)xp;
    f32x4 x1 = *(const f32x4*)(xp + 4);
    bf16x8 ah, al;
#pragma unroll
    for (int j = 0; j < 8; ++j) {
      float f = (j < 4) ? x0[j] : x1[j - 4];
      unsigned short h = f2bf(f);
      ah[j] = (short)h;
      al[j] = (short)f2bf(f - bf2f(h));
    }
#pragma unroll
    for (int t = 0; t < 24; ++t) {
      const unsigned short* wp = WT_hi + (t * 16 + hh) * 256 + kc * 32 + qq * 8;
      const unsigned short* wl = WT_lo + (t * 16 + hh) * 256 + kc * 32 + qq * 8;
      bf16x8 bh = *(const bf16x8*)wp;
      bf16x8 bl = *(const bf16x8*)wl;
      acc[t] = mfma16(ah, bh, acc[t]);
      acc[t] = mfma16(al, bh, acc[t]);
      acc[t] = mfma16(ah, bl, acc[t]);
    }
  }
  const long rowC = (long)blockIdx.x * 64 + wid * 16 + qq * 4;
  const int rowL = wid * 16 + qq * 4;
#pragma unroll
  for (int t = 0; t < 24; ++t) {
    const int col = t * 16 + hh;
    const int sec = t >> 3;        // 0=q 1=k 2=v (uniform per t)
    const int j = col & 127;
    const float bias = (sec == 0) ? bq[j] : (sec == 1) ? bk[j] : bv[j];
#pragma unroll
    for (int r = 0; r < 4; ++r) {
      float val = fmaxf(acc[t][r] + bias, 0.f);
      long o = (rowC + r) * 128 + j;
      if (sec == 0) {
        q_bf[o] = f2bf(val);
      } else if (sec == 1) {
        unsigned short h = f2bf(val);
        k_hi[o] = h;
        k_lo[o] = f2bf(val - bf2f(h));
      } else {
        vbuf[rowL + r][j] = f2bf(val);
      }
    }
  }
  __syncthreads();
  // cooperative transposed write: vT[(b*128 + h)*2048 + n]
  {
    const int tid = threadIdx.x;
    const int j = tid >> 1;          // h col 0..127
    const int half = tid & 1;        // n half (32 each)
    const long nbase = (long)blockIdx.x * 64;
    const int bb = (int)(nbase >> 11);
    const int noff = (int)(nbase & 2047);
    unsigned short* op = vT + ((long)bb * 128 + j) * 2048 + noff + half * 32;
#pragma unroll
    for (int g = 0; g < 4; ++g) {
      u32x4 w;
#pragma unroll
      for (int d = 0; d < 4; ++d) {
        int i = g * 8 + d * 2;
        w[d] = (unsigned int)vbuf[half * 32 + i][j] |
               ((unsigned int)vbuf[half * 32 + i + 1][j] << 16);
      }
      *(u32x4*)(op + g * 8) = w;
    }
  }
}

// ---------------------------------------------------------------------------
// Kernel 2: flash attention, zero LDS (K/V L2/L3-resident), bitmask.
// R2 structure: 512 blocks (b = idx>>4), 4 waves x 32 q-rows (ctq=2).
// Swapped QK^T: S^T = K·Q^T (C row=kv, col=q). Mask = 1 u64 bit-load per
// q-row per tile (prefetched 1 tile ahead); select replaces mask FMA.
// PV: O^T = V^T·P from pre-transposed vT; P redistribution via shfl.
// 2-pass hi/lo K for precision.
// ---------------------------------------------------------------------------
__global__ __launch_bounds__(256, 2) void attn_kernel(
    const unsigned short* __restrict__ q_bf, const unsigned short* __restrict__ k_hi,
    const unsigned short* __restrict__ k_lo, const unsigned short* __restrict__ vT,
    const unsigned long long* __restrict__ bits, unsigned short* __restrict__ out_att) {
  const int lane = threadIdx.x & 63, wid = threadIdx.x >> 6;
  const int qq = lane >> 4, hh = lane & 15;
  const int b = blockIdx.x >> 4;
  const int nb = blockIdx.x & 15;
  const long qbase = (long)b * 2048 + nb * 128 + wid * 32;
  const f32x4 zero4 = {0.f, 0.f, 0.f, 0.f};

  // hoisted Q fragments (B-operand): Q[q = ctq*16+hh][h = kc*32+qq*8+j]
  bf16x8 qh[2][4];
#pragma unroll
  for (int ctq = 0; ctq < 2; ++ctq)
#pragma unroll
    for (int kc = 0; kc < 4; ++kc)
      qh[ctq][kc] = *(const bf16x8*)(q_bf + (qbase + ctq * 16 + hh) * 128 + kc * 32 + qq * 8);

  const unsigned long long* br0 = bits + (qbase + hh) * 32;
  const unsigned long long* br1 = bits + (qbase + 16 + hh) * 32;
  const unsigned short* khl = k_hi + (long)b * 262144 + hh * 128 + qq * 8;
  const unsigned short* kll = k_lo + (long)b * 262144 + hh * 128 + qq * 8;
  const unsigned short* vl  = vT   + ((long)b * 128 + hh) * 2048 + qq * 8;

  f32x4 o_acc[8][2];
#pragma unroll
  for (int ht = 0; ht < 8; ++ht) { o_acc[ht][0] = zero4; o_acc[ht][1] = zero4; }
  float m_run[2] = {-3.0e38f, -3.0e38f};
  float l_run[2] = {0.f, 0.f};

  // prefetch bitmask for tile 0
  unsigned long long bc0 = br0[0];
  unsigned long long bc1 = br1[0];

  const int src0 = (((qq << 1)) & 3) * 16 + hh;
  const int src1 = (((qq << 1) + 1) & 3) * 16 + hh;
  const bool hiq = qq >= 2;

  for (int t = 0; t < 32; ++t) {
    const int koff = t * 8192;   // t*64 rows * 128

    // prefetch next tile's bitmask early
    unsigned long long bn0 = 0, bn1 = 0;
    if (t + 1 < 32) { bn0 = br0[t + 1]; bn1 = br1[t + 1]; }

    // S^T = K·Q^T (2-pass hi/lo K)
    f32x4 s[2][4];
#pragma unroll
    for (int m = 0; m < 4; ++m) { s[0][m] = zero4; s[1][m] = zero4; }
#pragma unroll
    for (int m = 0; m < 4; ++m) {
      bf16x8 khf[4], klf[4];
#pragma unroll
      for (int kc = 0; kc < 4; ++kc) {
        khf[kc] = *(const bf16x8*)(khl + koff + m * 2048 + kc * 32);
        klf[kc] = *(const bf16x8*)(kll + koff + m * 2048 + kc * 32);
      }
#pragma unroll
      for (int kc = 0; kc < 4; ++kc)
#pragma unroll
        for (int ctq = 0; ctq < 2; ++ctq) {
          s[ctq][m] = mfma16(khf[kc], qh[ctq][kc], s[ctq][m]);
          s[ctq][m] = mfma16(klf[kc], qh[ctq][kc], s[ctq][m]);
        }
    }

    // apply bitmask: s = bit ? s : -9e15  (exact: m*s - 9e15*(1-m) for m in {0,1})
    {
      const unsigned long long bb0 = bc0 >> (qq * 4);
      const unsigned long long bb1 = bc1 >> (qq * 4);
#pragma unroll
      for (int m = 0; m < 4; ++m)
#pragma unroll
        for (int r = 0; r < 4; ++r) {
          const int sh = m * 16 + r;
          s[0][m][r] = ((bb0 >> sh) & 1ull) ? s[0][m][r] : -NEGC;
          s[1][m][r] = ((bb1 >> sh) & 1ull) ? s[1][m][r] : -NEGC;
        }
    }

    // fp32 online softmax (per q col = hh; per-lane scalars)
    unsigned int pk[2][4][2];
#pragma unroll
    for (int ctq = 0; ctq < 2; ++ctq) {
      float mx = s[ctq][0][0];
#pragma unroll
      for (int m = 0; m < 4; ++m)
#pragma unroll
        for (int r = 0; r < 4; ++r) mx = fmaxf(mx, s[ctq][m][r]);
      mx = fmaxf(mx, __shfl_xor(mx, 16, 64));
      mx = fmaxf(mx, __shfl_xor(mx, 32, 64));
      float mnew = fmaxf(m_run[ctq], mx);
      float sc = exp2f((m_run[ctq] - mnew) * LOG2E);
      m_run[ctq] = mnew;
      float ps = 0.f;
#pragma unroll
      for (int m = 0; m < 4; ++m)
#pragma unroll
        for (int r = 0; r < 4; ++r) {
          float p = exp2f((s[ctq][m][r] - mnew) * LOG2E);
          s[ctq][m][r] = p;
          ps += p;
        }
      ps += __shfl_xor(ps, 16, 64);
      ps += __shfl_xor(ps, 32, 64);
      l_run[ctq] = l_run[ctq] * sc + ps;
#pragma unroll
      for (int ht = 0; ht < 8; ++ht) o_acc[ht][ctq] *= sc;
#pragma unroll
      for (int m = 0; m < 4; ++m) {
        pk[ctq][m][0] = pack2bf(s[ctq][m][0], s[ctq][m][1]);
        pk[ctq][m][1] = pack2bf(s[ctq][m][2], s[ctq][m][3]);
      }
    }

    // redistribute P (C layout) -> B-frag layout via shfl
    bf16x8 pb[2][2];
#pragma unroll
    for (int ctq = 0; ctq < 2; ++ctq)
#pragma unroll
      for (int c = 0; c < 2; ++c) {
        unsigned int a0 = (unsigned int)__shfl((int)pk[ctq][2 * c][0], src0, 64);
        unsigned int a1 = (unsigned int)__shfl((int)pk[ctq][2 * c][1], src0, 64);
        unsigned int a2 = (unsigned int)__shfl((int)pk[ctq][2 * c][0], src1, 64);
        unsigned int a3 = (unsigned int)__shfl((int)pk[ctq][2 * c][1], src1, 64);
        unsigned int b0 = (unsigned int)__shfl((int)pk[ctq][2 * c + 1][0], src0, 64);
        unsigned int b1 = (unsigned int)__shfl((int)pk[ctq][2 * c + 1][1], src0, 64);
        unsigned int b2 = (unsigned int)__shfl((int)pk[ctq][2 * c + 1][0], src1, 64);
        unsigned int b3 = (unsigned int)__shfl((int)pk[ctq][2 * c + 1][1], src1, 64);
        u32x4 w;
        w[0] = hiq ? b0 : a0;
        w[1] = hiq ? b1 : a1;
        w[2] = hiq ? b2 : a2;
        w[3] = hiq ? b3 : a3;
        pb[ctq][c] = __builtin_bit_cast(bf16x8, w);
      }

    // O^T += V^T · P
#pragma unroll
    for (int ht = 0; ht < 8; ++ht)
#pragma unroll
      for (int c = 0; c < 2; ++c) {
        bf16x8 vf = *(const bf16x8*)(vl + ht * 32768 + t * 64 + c * 32);
#pragma unroll
        for (int ctq = 0; ctq < 2; ++ctq)
          o_acc[ht][ctq] = mfma16(vf, pb[ctq][c], o_acc[ht][ctq]);
      }

    bc0 = bn0;
    bc1 = bn1;
  }

  // epilogue: normalize, store bf16. O^T frag: row h = ht*16+qq*4+r, col q = hh.
#pragma unroll
  for (int ctq = 0; ctq < 2; ++ctq) {
    float inv = 1.0f / l_run[ctq];
    const long row = qbase + ctq * 16 + hh;
#pragma unroll
    for (int ht = 0; ht < 8; ++ht) {
      f32x4 o = o_acc[ht][ctq];
      uint2 w;
      w.x = pack2bf(o[0] * inv, o[1] * inv);
      w.y = pack2bf(o[2] * inv, o[3] * inv);
      *(uint2*)(out_att + row * 128 + ht * 16 + qq * 4) = w;
    }
  }
}

// ---------------------------------------------------------------------------
// Kernel 3: out = relu(out_att @ Wout + bout) fused with the three heads.
// ---------------------------------------------------------------------------
__global__ __launch_bounds__(256) void wout_heads_kernel(
    const unsigned short* __restrict__ out_att, const unsigned short* __restrict__ WoutT,
    const float* __restrict__ bout,
    const float* __restrict__ Wval, const float* __restrict__ bval,
    const float* __restrict__ Wadv1, const float* __restrict__ badv1,
    const float* __restrict__ Wadv2, const float* __restrict__ badv2,
    float* __restrict__ value, float* __restrict__ adv1, float* __restrict__ adv2) {
  const int lane = threadIdx.x & 63, wid = threadIdx.x >> 6;
  const int qq = lane >> 4, hh = lane & 15;
  const long rowA = (long)blockIdx.x * 64 + wid * 16 + hh;
  const f32x4 zero4 = {0.f, 0.f, 0.f, 0.f};
  f32x4 acc[8];
#pragma unroll
  for (int t = 0; t < 8; ++t) acc[t] = zero4;
#pragma unroll
  for (int kc = 0; kc < 4; ++kc) {
    bf16x8 af = *(const bf16x8*)(out_att + rowA * 128 + kc * 32 + qq * 8);
#pragma unroll
    for (int t = 0; t < 8; ++t) {
      bf16x8 bf = *(const bf16x8*)(WoutT + (t * 16 + hh) * 128 + kc * 32 + qq * 8);
      acc[t] = mfma16(af, bf, acc[t]);
    }
  }
  float pv[4] = {0.f, 0.f, 0.f, 0.f};
  float pa1[4][8], pa2[4][8];
#pragma unroll
  for (int r = 0; r < 4; ++r)
#pragma unroll
    for (int j = 0; j < 8; ++j) { pa1[r][j] = 0.f; pa2[r][j] = 0.f; }
#pragma unroll
  for (int t = 0; t < 8; ++t) {
    const int col = t * 16 + hh;
    const float bo = bout[col];
    const float wv = Wval[col];
    const f32x4 w1a = *(const f32x4*)(Wadv1 + col * 8);
    const f32x4 w1b = *(const f32x4*)(Wadv1 + col * 8 + 4);
    const f32x4 w2a = *(const f32x4*)(Wadv2 + col * 8);
    const f32x4 w2b = *(const f32x4*)(Wadv2 + col * 8 + 4);
#pragma unroll
    for (int r = 0; r < 4; ++r) {
      float h = fmaxf(acc[t][r] + bo, 0.f);
      pv[r] += h * wv;
#pragma unroll
      for (int j = 0; j < 4; ++j) {
        pa1[r][j]     += h * w1a[j];
        pa1[r][4 + j] += h * w1b[j];
        pa2[r][j]     += h * w2a[j];
        pa2[r][4 + j] += h * w2b[j];
      }
    }
  }
#pragma unroll
  for (int r = 0; r < 4; ++r) {
#pragma unroll
    for (int s = 1; s < 16; s <<= 1) {
      pv[r] += __shfl_xor(pv[r], s, 64);
#pragma unroll
      for (int j = 0; j < 8; ++j) {
        pa1[r][j] += __shfl_xor(pa1[r][j], s, 64);
        pa2[r][j] += __shfl_xor(pa2[r][j], s, 64);
      }
    }
  }
  if (hh == 0) {
    const float bv0 = bval[0];
#pragma unroll
    for (int r = 0; r < 4; ++r) {
      const long row = (long)blockIdx.x * 64 + wid * 16 + qq * 4 + r;
      value[row] = pv[r] + bv0;
#pragma unroll
      for (int j = 0; j < 8; ++j) {
        adv1[row * 8 + j] = pa1[r][j] + badv1[j];
        adv2[row * 8 + j] = pa2[r][j] + badv2[j];
      }
    }
  }
}

// ---------------------------------------------------------------------------
// Kernel 4: per-batch column sums of adv1/adv2 over N (deterministic tree).
// ---------------------------------------------------------------------------
__global__ __launch_bounds__(256) void sums_kernel(const float* __restrict__ adv1,
                                                   const float* __restrict__ adv2,
                                                   float* __restrict__ sums) {
  const int b = blockIdx.x, tid = threadIdx.x;
  __shared__ float red[4][16];
  float p[16];
#pragma unroll
  for (int j = 0; j < 16; ++j) p[j] = 0.f;
  for (int n = tid; n < 2048; n += 256) {
    const long row = (long)b * 2048 + n;
    const f32x4 a1a = *(const f32x4*)(adv1 + row * 8);
    const f32x4 a1b = *(const f32x4*)(adv1 + row * 8 + 4);
    const f32x4 a2a = *(const f32x4*)(adv2 + row * 8);
    const f32x4 a2b = *(const f32x4*)(adv2 + row * 8 + 4);
#pragma unroll
    for (int j = 0; j < 4; ++j) {
      p[j] += a1a[j]; p[4 + j] += a1b[j];
      p[8 + j] += a2a[j]; p[12 + j] += a2b[j];
    }
  }
#pragma unroll
  for (int s = 1; s < 64; s <<= 1)
#pragma unroll
    for (int j = 0; j < 16; ++j) p[j] += __shfl_xor(p[j], s, 64);
  const int wid = tid >> 6;
  if ((tid & 63) == 0)
#pragma unroll
    for (int j = 0; j < 16; ++j) red[wid][j] = p[j];
  __syncthreads();
  if (tid < 16)
    sums[b * 16 + tid] = red[0][tid] + red[1][tid] + red[2][tid] + red[3][tid];
}

// ---------------------------------------------------------------------------
// Kernel 5: q1/q2 = value + adv - mean(adv). Output: [q1 | q2] fp32 flat.
// ---------------------------------------------------------------------------
__global__ void combine_kernel(const float* __restrict__ value, const float* __restrict__ adv1,
                               const float* __restrict__ adv2, const float* __restrict__ sums,
                               float* __restrict__ out) {
  const int idx = blockIdx.x * 256 + threadIdx.x;   // 0 .. 1048575
  const int half = 524288;
  const int which = (idx >= half) ? 1 : 0;
  const int rem = idx - which * half;
  const int b = rem >> 14;
  const int r2 = rem & 16383;
  const int n = r2 >> 3, j = r2 & 7;
  const long row = (long)b * 2048 + n;
  const float* adv = which ? adv2 : adv1;
  const float mean = sums[b * 16 + which * 8 + j] * (1.0f / 2048.0f);
  out[idx] = value[row] + adv[row * 8 + j] - mean;
}

// ---------------------------------------------------------------------------
extern "C" void kernel_launch(void* const* d_in, const int* in_sizes, int n_in,
                              void* d_out, int out_size, void* d_ws, size_t ws_size,
                              hipStream_t stream) {
  const float* x     = (const float*)d_in[0];
  const float* mask  = (const float*)d_in[1];
  const float* Wv    = (const float*)d_in[2];
  const float* bv    = (const float*)d_in[3];
  const float* Wk    = (const float*)d_in[4];
  const float* bk    = (const float*)d_in[5];
  const float* Wq    = (const float*)d_in[6];
  const float* bq    = (const float*)d_in[7];
  const float* Wout  = (const float*)d_in[8];
  const float* bout  = (const float*)d_in[9];
  const float* Wval  = (const float*)d_in[10];
  const float* bval  = (const float*)d_in[11];
  const float* Wadv1 = (const float*)d_in[12];
  const float* badv1 = (const float*)d_in[13];
  const float* Wadv2 = (const float*)d_in[14];
  const float* badv2 = (const float*)d_in[15];
  float* out = (float*)d_out;
  char* ws = (char*)d_ws;

  // workspace layout (bytes)
  unsigned short* q_bf   = (unsigned short*)(ws + 0);
  unsigned short* k_hi   = (unsigned short*)(ws + 16777216);
  unsigned short* k_lo   = (unsigned short*)(ws + 33554432);
  unsigned short* vT     = (unsigned short*)(ws + 50331648);
  unsigned short* out_at = (unsigned short*)(ws + 67108864);
  float* value = (float*)(ws + 83886080);
  float* adv1  = (float*)(ws + 84148224);
  float* adv2  = (float*)(ws + 86245376);
  float* sums  = (float*)(ws + 88342528);
  unsigned short* WT_hi = (unsigned short*)(ws + 88344576);
  unsigned short* WT_lo = (unsigned short*)(ws + 88541184);
  unsigned short* WoutT = (unsigned short*)(ws + 88737792);
  unsigned long long* bits = (unsigned long long*)(ws + 88770560);  // 16.8 MB

  prepack_kernel<<<2048, 256, 0, stream>>>(mask, bits);
  prep_kernel<<<448, 256, 0, stream>>>(Wv, Wk, Wq, Wout, WT_hi, WT_lo, WoutT);
  proj_kernel<<<1024, 256, 0, stream>>>(x, WT_hi, WT_lo, bq, bk, bv,
                                        q_bf, k_hi, k_lo, vT);
  attn_kernel<<<512, 256, 0, stream>>>(q_bf, k_hi, k_lo, vT, bits, out_at);
  wout_heads_kernel<<<1024, 256, 0, stream>>>(out_at, WoutT, bout, Wval, bval,
                                              Wadv1, badv1, Wadv2, badv2,
                                              value, adv1, adv2);
  sums_kernel<<<32, 256, 0, stream>>>(adv1, adv2, sums);
  combine_kernel<<<4096, 256, 0, stream>>>(value, adv1, adv2, sums, out);
}

// Round 5
// 362.868 us; speedup vs baseline: 3.1365x; 2.0443x over previous
//
#include <hip/hip_runtime.h>
#include <hip/hip_bf16.h>

// BranchingQNetwork fused forward for MI355X (gfx950).
// B=32, N=2048, OBS=256, HID=128, n1=n2=8.
// v5: LDS-shared K/V/W (the L1 path was the bottleneck: ~13B/cy/CU effective;
// LDS gives ~112B/cy). Pre-fragged global layouts -> contiguous staging +
// conflict-free lane*16 ds_reads. k_lo dropped (absmax headroom). Defer-max.

typedef __attribute__((ext_vector_type(4))) float f32x4;
typedef __attribute__((ext_vector_type(8))) short bf16x8;
typedef __attribute__((ext_vector_type(4))) unsigned int u32x4;

#define LOG2E 1.44269504088896340736f
#define NEGC 9.0e15f

static __device__ __forceinline__ unsigned short f2bf(float f) {
  unsigned int x = __builtin_bit_cast(unsigned int, f);
  unsigned int r = (x + 0x7fffu + ((x >> 16) & 1u)) >> 16;   // RNE
  return (unsigned short)r;
}
static __device__ __forceinline__ float bf2f(unsigned short u) {
  return __builtin_bit_cast(float, ((unsigned int)u) << 16);
}
static __device__ __forceinline__ unsigned int pack2bf(float lo, float hi) {
  return (unsigned int)f2bf(lo) | ((unsigned int)f2bf(hi) << 16);
}
static __device__ __forceinline__ f32x4 mfma16(bf16x8 a, bf16x8 b, f32x4 c) {
  return __builtin_amdgcn_mfma_f32_16x16x32_bf16(a, b, c, 0, 0, 0);
}

// ---------------------------------------------------------------------------
// Kernel P: mask prepack. mask fp32 -> bitmask u64; bits[row*32+t] covers
// kv = t*64..t*64+63. 537 MB -> 16.8 MB.
// ---------------------------------------------------------------------------
__global__ __launch_bounds__(256) void prepack_kernel(const float* __restrict__ mask,
                                                      unsigned long long* __restrict__ bits) {
  const int lane = threadIdx.x & 63;
  const int gwave = (blockIdx.x << 2) | (threadIdx.x >> 6);  // 8192 waves
  for (int r = 0; r < 8; ++r) {
    const long row = (long)gwave * 8 + r;
    const float* mp = mask + row * 2048 + lane;
    unsigned long long* op = bits + row * 32;
#pragma unroll
    for (int g = 0; g < 8; ++g) {
      float f0 = mp[(g * 4 + 0) * 64];
      float f1 = mp[(g * 4 + 1) * 64];
      float f2 = mp[(g * 4 + 2) * 64];
      float f3 = mp[(g * 4 + 3) * 64];
      unsigned long long b0 = __ballot(f0 != 0.0f);
      unsigned long long b1 = __ballot(f1 != 0.0f);
      unsigned long long b2 = __ballot(f2 != 0.0f);
      unsigned long long b3 = __ballot(f3 != 0.0f);
      if (lane == 0) {
        ulonglong2 w0 = {b0, b1};
        ulonglong2 w1 = {b2, b3};
        *(ulonglong2*)(op + g * 4) = w0;
        *(ulonglong2*)(op + g * 4 + 2) = w1;
      }
    }
  }
}

// ---------------------------------------------------------------------------
// Kernel 0: weight prep into FRAG-LINEAR layouts.
// Wf[(kc*24 + t)*64 + lane][e] = Wsec[k = kc*32 + (lane>>4)*8 + e]
//                                    [j = (t&7)*16 + (lane&15)]
// with sec = t>>3 (0=q,1=k,2=v). hi/lo split. WoutT unchanged ([j][k]).
// ---------------------------------------------------------------------------
__global__ __launch_bounds__(256) void prep_kernel(
    const float* __restrict__ Wv, const float* __restrict__ Wk,
    const float* __restrict__ Wq, const float* __restrict__ Wout,
    unsigned short* __restrict__ Wf_hi, unsigned short* __restrict__ Wf_lo,
    unsigned short* __restrict__ WoutT) {
  int gid = blockIdx.x * 256 + threadIdx.x;
  if (gid < 12288) {                 // (kc, t, lane)
    int kc = gid / 1536;
    int rem = gid - kc * 1536;
    int t = rem >> 6, lane = rem & 63;
    int hf = lane & 15, qf = lane >> 4;
    int sec = t >> 3;
    int j = (t & 7) * 16 + hf;
    const float* W = (sec == 0) ? Wq : (sec == 1) ? Wk : Wv;
#pragma unroll
    for (int e = 0; e < 8; ++e) {
      int k = kc * 32 + qf * 8 + e;
      float w = W[k * 128 + j];
      unsigned short hi = f2bf(w);
      Wf_hi[gid * 8 + e] = hi;
      Wf_lo[gid * 8 + e] = f2bf(w - bf2f(hi));
    }
  } else if (gid < 12288 + 16384) {
    int i2 = gid - 12288;
    int j = i2 >> 7, c = i2 & 127;
    WoutT[i2] = f2bf(Wout[c * 128 + j]);
  }
}

// ---------------------------------------------------------------------------
// Kernel 1: fused QKV projection. 512 threads (8 waves), 128 rows/block.
// W staged per-kc in LDS (one VMEM copy per block, shared by 8 waves).
// 3-pass hi/lo x*W MFMA. Outputs routed through LDS vbuf -> coalesced stores:
//   q  -> row-major q_bf[row][128]
//   k  -> frag-linear Kf[(b*32+t)*16 + m*4+kc][lane][8]   (K rows=kv)
//   v  -> frag-linear Vf[(b*32+t)*16 + ht*2+c][lane][8]   (V^T: [h][n])
// ---------------------------------------------------------------------------
__global__ __launch_bounds__(512, 2) void proj_kernel(
    const float* __restrict__ x,
    const unsigned short* __restrict__ Wf_hi, const unsigned short* __restrict__ Wf_lo,
    const float* __restrict__ bq, const float* __restrict__ bk, const float* __restrict__ bv,
    unsigned short* __restrict__ q_bf, unsigned short* __restrict__ Kf,
    unsigned short* __restrict__ Vf) {
  __shared__ bf16x8 wst_hi[1536];              // 24 KB: Wf slice for one kc
  __shared__ bf16x8 wst_lo[1536];              // 24 KB
  __shared__ unsigned short vbuf[128][136];    // 34.8 KB staging for outputs

  const int tid = threadIdx.x;
  const int lane = tid & 63, wid = tid >> 6;
  const int qq = lane >> 4, hh = lane & 15;
  const long rbase = (long)blockIdx.x * 128;
  const long rowA = rbase + wid * 16 + hh;
  const f32x4 zero4 = {0.f, 0.f, 0.f, 0.f};
  f32x4 acc[24];
#pragma unroll
  for (int t = 0; t < 24; ++t) acc[t] = zero4;

  for (int kc = 0; kc < 8; ++kc) {
    __syncthreads();   // protect wst reuse
    // stage W slice for this kc: 2x 1536 bf16x8, 512 threads -> 3 iters each
#pragma unroll
    for (int i = 0; i < 3; ++i) {
      int idx = i * 512 + tid;
      wst_hi[idx] = *(const bf16x8*)(Wf_hi + ((long)kc * 1536 + idx) * 8);
      wst_lo[idx] = *(const bf16x8*)(Wf_lo + ((long)kc * 1536 + idx) * 8);
    }
    __syncthreads();

    const float* xp = x + rowA * 256 + kc * 32 + qq * 8;
    f32x4 x0 = *(const f32x4*)xp;
    f32x4 x1 = *(const f32x4*)(xp + 4);
    bf16x8 ah, al;
#pragma unroll
    for (int j = 0; j < 8; ++j) {
      float f = (j < 4) ? x0[j] : x1[j - 4];
      unsigned short h = f2bf(f);
      ah[j] = (short)h;
      al[j] = (short)f2bf(f - bf2f(h));
    }
#pragma unroll
    for (int t = 0; t < 24; ++t) {
      bf16x8 bh = wst_hi[t * 64 + lane];
      bf16x8 bl = wst_lo[t * 64 + lane];
      acc[t] = mfma16(ah, bh, acc[t]);
      acc[t] = mfma16(al, bh, acc[t]);
      acc[t] = mfma16(ah, bl, acc[t]);
    }
  }

  const int rowL = wid * 16 + qq * 4;
  const int b = (int)(rbase >> 11);
  const int tbase = (int)((rbase & 2047) >> 6);   // 2 K/V tiles per block

  for (int sec = 0; sec < 3; ++sec) {
    __syncthreads();   // vbuf free
#pragma unroll
    for (int tp = 0; tp < 8; ++tp) {
      const int t = sec * 8 + tp;
      const int j = tp * 16 + hh;
      const float bias = (sec == 0) ? bq[j] : (sec == 1) ? bk[j] : bv[j];
#pragma unroll
      for (int r = 0; r < 4; ++r) {
        unsigned short h = f2bf(fmaxf(acc[t][r] + bias, 0.f));
        if (sec == 2) vbuf[j][rowL + r] = h;       // V transposed: [h][n]
        else          vbuf[rowL + r][j] = h;
      }
    }
    __syncthreads();
    if (sec == 0) {
      // q: row-major coalesced store
      const int row = tid >> 2, ch = tid & 3;
      bf16x8 w = *(const bf16x8*)&vbuf[row][ch * 32];
      bf16x8 w2 = *(const bf16x8*)&vbuf[row][ch * 32 + 8];
      bf16x8 w3 = *(const bf16x8*)&vbuf[row][ch * 32 + 16];
      bf16x8 w4 = *(const bf16x8*)&vbuf[row][ch * 32 + 24];
      unsigned short* op = q_bf + (rbase + row) * 128 + ch * 32;
      *(bf16x8*)op = w; *(bf16x8*)(op + 8) = w2;
      *(bf16x8*)(op + 16) = w3; *(bf16x8*)(op + 24) = w4;
    } else if (sec == 1) {
      // k -> Kf frag order
#pragma unroll
      for (int it = 0; it < 4; ++it) {
        int gid = it * 512 + tid;                    // (tt, m, kc, lane)
        int tt = gid >> 10, m = (gid >> 8) & 3, kc = (gid >> 6) & 3, ln = gid & 63;
        int hf = ln & 15, qf = ln >> 4;
        bf16x8 w = *(const bf16x8*)&vbuf[tt * 64 + m * 16 + hf][kc * 32 + qf * 8];
        long off = (((long)(b * 32 + tbase + tt) * 16 + m * 4 + kc) * 64 + ln) * 8;
        *(bf16x8*)(Kf + off) = w;
      }
    } else {
      // v -> Vf frag order (from transposed vbuf[h][n])
#pragma unroll
      for (int it = 0; it < 4; ++it) {
        int gid = it * 512 + tid;                    // (tt, ht, c, lane)
        int tt = gid >> 10, ht = (gid >> 7) & 7, c = (gid >> 6) & 1, ln = gid & 63;
        int hf = ln & 15, qf = ln >> 4;
        bf16x8 w = *(const bf16x8*)&vbuf[ht * 16 + hf][tt * 64 + c * 32 + qf * 8];
        long off = (((long)(b * 32 + tbase + tt) * 16 + ht * 2 + c) * 64 + ln) * 8;
        *(bf16x8*)(Vf + off) = w;
      }
    }
  }
}

// ---------------------------------------------------------------------------
// Kernel 2: flash attention, LDS-shared K/V (frag-linear staging).
// 256 blocks x 512 threads (8 waves x 32 q-rows = 256 rows/block), all kv.
// Double-buffered reg-staged K/V (issue-early/write-late). Swapped QK^T,
// bitmask select, fp32 online softmax w/ defer-max, shfl P-redistribute.
// ---------------------------------------------------------------------------
__global__ __launch_bounds__(512, 2) void attn_kernel(
    const unsigned short* __restrict__ q_bf, const unsigned short* __restrict__ Kf,
    const unsigned short* __restrict__ Vf,
    const unsigned long long* __restrict__ bits, unsigned short* __restrict__ out_att) {
  __shared__ bf16x8 kls[2][1024];   // 2 x 16 KB
  __shared__ bf16x8 vls[2][1024];   // 2 x 16 KB

  const int tid = threadIdx.x;
  const int lane = tid & 63, wid = tid >> 6;
  const int qq = lane >> 4, hh = lane & 15;
  // XCD-aware: each XCD's blocks serve 4 batches
  const int orig = blockIdx.x;
  const int b = ((orig & 7) << 2) | ((orig >> 3) & 3);
  const int nb = orig >> 5;
  const long qbase = (long)b * 2048 + nb * 256 + wid * 32;

  const f32x4 zero4 = {0.f, 0.f, 0.f, 0.f};

  // Q fragments (B-operand): Q[q = ctq*16+hh][k = kc*32+qq*8+e]
  bf16x8 qh[2][4];
#pragma unroll
  for (int ctq = 0; ctq < 2; ++ctq)
#pragma unroll
    for (int kc = 0; kc < 4; ++kc)
      qh[ctq][kc] = *(const bf16x8*)(q_bf + (qbase + ctq * 16 + hh) * 128 + kc * 32 + qq * 8);

  const unsigned long long* br0 = bits + (qbase + hh) * 32;
  const unsigned long long* br1 = bits + (qbase + 16 + hh) * 32;
  const unsigned short* kf0 = Kf + (long)(b * 32) * 8192;
  const unsigned short* vf0 = Vf + (long)(b * 32) * 8192;

  f32x4 o_acc[8][2];
#pragma unroll
  for (int ht = 0; ht < 8; ++ht) { o_acc[ht][0] = zero4; o_acc[ht][1] = zero4; }
  float m_run[2] = {-3.0e38f, -3.0e38f};
  float l_run[2] = {0.f, 0.f};

  // staging: wave wid owns segments wid*4 .. wid*4+3 (seg<16: K, else V)
  bf16x8 stg[4];
  const int seg0 = wid * 4;
  auto LOADREG = [&](int t) {
#pragma unroll
    for (int i = 0; i < 4; ++i) {
      int seg = seg0 + i;
      const unsigned short* src = (seg < 16)
          ? kf0 + (long)t * 8192 + (seg * 64 + lane) * 8
          : vf0 + (long)t * 8192 + ((seg - 16) * 64 + lane) * 8;
      stg[i] = *(const bf16x8*)src;
    }
  };
  auto WRITEBUF = [&](int nb2) {
#pragma unroll
    for (int i = 0; i < 4; ++i) {
      int seg = seg0 + i;
      if (seg < 16) kls[nb2][seg * 64 + lane] = stg[i];
      else          vls[nb2][(seg - 16) * 64 + lane] = stg[i];
    }
  };

  LOADREG(0);
  WRITEBUF(0);
  LOADREG(1);
  __syncthreads();

  unsigned long long bc0 = br0[0];
  unsigned long long bc1 = br1[0];

  const int src0 = (((qq << 1)) & 3) * 16 + hh;
  const int src1 = (((qq << 1) + 1) & 3) * 16 + hh;
  const bool hiq = qq >= 2;
  int cur = 0;

  for (int t = 0; t < 32; ++t) {
    unsigned long long bn0 = 0, bn1 = 0;
    if (t + 1 < 32) { bn0 = br0[t + 1]; bn1 = br1[t + 1]; }

    // S^T = K·Q^T from LDS (conflict-free lane*16 reads)
    f32x4 s[2][4];
#pragma unroll
    for (int m = 0; m < 4; ++m) { s[0][m] = zero4; s[1][m] = zero4; }
#pragma unroll
    for (int m = 0; m < 4; ++m) {
      bf16x8 khf[4];
#pragma unroll
      for (int kc = 0; kc < 4; ++kc) khf[kc] = kls[cur][(m * 4 + kc) * 64 + lane];
#pragma unroll
      for (int kc = 0; kc < 4; ++kc)
#pragma unroll
        for (int ctq = 0; ctq < 2; ++ctq)
          s[ctq][m] = mfma16(khf[kc], qh[ctq][kc], s[ctq][m]);
    }

    // bitmask select
    {
      const unsigned long long bb0 = bc0 >> (qq * 4);
      const unsigned long long bb1 = bc1 >> (qq * 4);
#pragma unroll
      for (int m = 0; m < 4; ++m)
#pragma unroll
        for (int r = 0; r < 4; ++r) {
          const int sh = m * 16 + r;
          s[0][m][r] = ((bb0 >> sh) & 1ull) ? s[0][m][r] : -NEGC;
          s[1][m][r] = ((bb1 >> sh) & 1ull) ? s[1][m][r] : -NEGC;
        }
    }

    // fp32 online softmax with defer-max (rescale only when max grows)
    unsigned int pk[2][4][2];
#pragma unroll
    for (int ctq = 0; ctq < 2; ++ctq) {
      float mx = s[ctq][0][0];
#pragma unroll
      for (int m = 0; m < 4; ++m)
#pragma unroll
        for (int r = 0; r < 4; ++r) mx = fmaxf(mx, s[ctq][m][r]);
      mx = fmaxf(mx, __shfl_xor(mx, 16, 64));
      mx = fmaxf(mx, __shfl_xor(mx, 32, 64));
      if (__any(mx > m_run[ctq])) {
        float mnew = fmaxf(m_run[ctq], mx);
        float sc = exp2f((m_run[ctq] - mnew) * LOG2E);
        m_run[ctq] = mnew;
        l_run[ctq] *= sc;
#pragma unroll
        for (int ht = 0; ht < 8; ++ht) o_acc[ht][ctq] *= sc;
      }
      float ps = 0.f;
#pragma unroll
      for (int m = 0; m < 4; ++m)
#pragma unroll
        for (int r = 0; r < 4; ++r) {
          float p = exp2f((s[ctq][m][r] - m_run[ctq]) * LOG2E);
          s[ctq][m][r] = p;
          ps += p;
        }
      ps += __shfl_xor(ps, 16, 64);
      ps += __shfl_xor(ps, 32, 64);
      l_run[ctq] += ps;
#pragma unroll
      for (int m = 0; m < 4; ++m) {
        pk[ctq][m][0] = pack2bf(s[ctq][m][0], s[ctq][m][1]);
        pk[ctq][m][1] = pack2bf(s[ctq][m][2], s[ctq][m][3]);
      }
    }

    // redistribute P (C layout) -> B-frag layout via shfl
    bf16x8 pb[2][2];
#pragma unroll
    for (int ctq = 0; ctq < 2; ++ctq)
#pragma unroll
      for (int c = 0; c < 2; ++c) {
        unsigned int a0 = (unsigned int)__shfl((int)pk[ctq][2 * c][0], src0, 64);
        unsigned int a1 = (unsigned int)__shfl((int)pk[ctq][2 * c][1], src0, 64);
        unsigned int a2 = (unsigned int)__shfl((int)pk[ctq][2 * c][0], src1, 64);
        unsigned int a3 = (unsigned int)__shfl((int)pk[ctq][2 * c][1], src1, 64);
        unsigned int b0 = (unsigned int)__shfl((int)pk[ctq][2 * c + 1][0], src0, 64);
        unsigned int b1 = (unsigned int)__shfl((int)pk[ctq][2 * c + 1][1], src0, 64);
        unsigned int b2 = (unsigned int)__shfl((int)pk[ctq][2 * c + 1][0], src1, 64);
        unsigned int b3 = (unsigned int)__shfl((int)pk[ctq][2 * c + 1][1], src1, 64);
        u32x4 w;
        w[0] = hiq ? b0 : a0;
        w[1] = hiq ? b1 : a1;
        w[2] = hiq ? b2 : a2;
        w[3] = hiq ? b3 : a3;
        pb[ctq][c] = __builtin_bit_cast(bf16x8, w);
      }

    // O^T += V^T · P from LDS
#pragma unroll
    for (int ht = 0; ht < 8; ++ht)
#pragma unroll
      for (int c = 0; c < 2; ++c) {
        bf16x8 vf = vls[cur][(ht * 2 + c) * 64 + lane];
#pragma unroll
        for (int ctq = 0; ctq < 2; ++ctq)
          o_acc[ht][ctq] = mfma16(vf, pb[ctq][c], o_acc[ht][ctq]);
      }

    __syncthreads();
    if (t + 1 < 32) WRITEBUF(cur ^ 1);   // t+1 data (compiler waits vmcnt)
    if (t + 2 < 32) LOADREG(t + 2);      // in flight during next compute
    __syncthreads();
    cur ^= 1;
    bc0 = bn0;
    bc1 = bn1;
  }

  // epilogue: normalize, store bf16. O^T frag: row h = ht*16+qq*4+r, col q=hh.
#pragma unroll
  for (int ctq = 0; ctq < 2; ++ctq) {
    float inv = 1.0f / l_run[ctq];
    const long row = qbase + ctq * 16 + hh;
#pragma unroll
    for (int ht = 0; ht < 8; ++ht) {
      f32x4 o = o_acc[ht][ctq];
      uint2 w;
      w.x = pack2bf(o[0] * inv, o[1] * inv);
      w.y = pack2bf(o[2] * inv, o[3] * inv);
      *(uint2*)(out_att + row * 128 + ht * 16 + qq * 4) = w;
    }
  }
}

// ---------------------------------------------------------------------------
// Kernel 3: out = relu(out_att @ Wout + bout) fused with the three heads.
// ---------------------------------------------------------------------------
__global__ __launch_bounds__(256) void wout_heads_kernel(
    const unsigned short* __restrict__ out_att, const unsigned short* __restrict__ WoutT,
    const float* __restrict__ bout,
    const float* __restrict__ Wval, const float* __restrict__ bval,
    const float* __restrict__ Wadv1, const float* __restrict__ badv1,
    const float* __restrict__ Wadv2, const float* __restrict__ badv2,
    float* __restrict__ value, float* __restrict__ adv1, float* __restrict__ adv2) {
  const int lane = threadIdx.x & 63, wid = threadIdx.x >> 6;
  const int qq = lane >> 4, hh = lane & 15;
  const long rowA = (long)blockIdx.x * 64 + wid * 16 + hh;
  const f32x4 zero4 = {0.f, 0.f, 0.f, 0.f};
  f32x4 acc[8];
#pragma unroll
  for (int t = 0; t < 8; ++t) acc[t] = zero4;
#pragma unroll
  for (int kc = 0; kc < 4; ++kc) {
    bf16x8 af = *(const bf16x8*)(out_att + rowA * 128 + kc * 32 + qq * 8);
#pragma unroll
    for (int t = 0; t < 8; ++t) {
      bf16x8 bf = *(const bf16x8*)(WoutT + (t * 16 + hh) * 128 + kc * 32 + qq * 8);
      acc[t] = mfma16(af, bf, acc[t]);
    }
  }
  float pv[4] = {0.f, 0.f, 0.f, 0.f};
  float pa1[4][8], pa2[4][8];
#pragma unroll
  for (int r = 0; r < 4; ++r)
#pragma unroll
    for (int j = 0; j < 8; ++j) { pa1[r][j] = 0.f; pa2[r][j] = 0.f; }
#pragma unroll
  for (int t = 0; t < 8; ++t) {
    const int col = t * 16 + hh;
    const float bo = bout[col];
    const float wv = Wval[col];
    const f32x4 w1a = *(const f32x4*)(Wadv1 + col * 8);
    const f32x4 w1b = *(const f32x4*)(Wadv1 + col * 8 + 4);
    const f32x4 w2a = *(const f32x4*)(Wadv2 + col * 8);
    const f32x4 w2b = *(const f32x4*)(Wadv2 + col * 8 + 4);
#pragma unroll
    for (int r = 0; r < 4; ++r) {
      float h = fmaxf(acc[t][r] + bo, 0.f);
      pv[r] += h * wv;
#pragma unroll
      for (int j = 0; j < 4; ++j) {
        pa1[r][j]     += h * w1a[j];
        pa1[r][4 + j] += h * w1b[j];
        pa2[r][j]     += h * w2a[j];
        pa2[r][4 + j] += h * w2b[j];
      }
    }
  }
#pragma unroll
  for (int r = 0; r < 4; ++r) {
#pragma unroll
    for (int s = 1; s < 16; s <<= 1) {
      pv[r] += __shfl_xor(pv[r], s, 64);
#pragma unroll
      for (int j = 0; j < 8; ++j) {
        pa1[r][j] += __shfl_xor(pa1[r][j], s, 64);
        pa2[r][j] += __shfl_xor(pa2[r][j], s, 64);
      }
    }
  }
  if (hh == 0) {
    const float bv0 = bval[0];
#pragma unroll
    for (int r = 0; r < 4; ++r) {
      const long row = (long)blockIdx.x * 64 + wid * 16 + qq * 4 + r;
      value[row] = pv[r] + bv0;
#pragma unroll
      for (int j = 0; j < 8; ++j) {
        adv1[row * 8 + j] = pa1[r][j] + badv1[j];
        adv2[row * 8 + j] = pa2[r][j] + badv2[j];
      }
    }
  }
}

// ---------------------------------------------------------------------------
// Kernel 4: per-batch column sums of adv1/adv2 over N (deterministic tree).
// ---------------------------------------------------------------------------
__global__ __launch_bounds__(256) void sums_kernel(const float* __restrict__ adv1,
                                                   const float* __restrict__ adv2,
                                                   float* __restrict__ sums) {
  const int b = blockIdx.x, tid = threadIdx.x;
  __shared__ float red[4][16];
  float p[16];
#pragma unroll
  for (int j = 0; j < 16; ++j) p[j] = 0.f;
  for (int n = tid; n < 2048; n += 256) {
    const long row = (long)b * 2048 + n;
    const f32x4 a1a = *(const f32x4*)(adv1 + row * 8);
    const f32x4 a1b = *(const f32x4*)(adv1 + row * 8 + 4);
    const f32x4 a2a = *(const f32x4*)(adv2 + row * 8);
    const f32x4 a2b = *(const f32x4*)(adv2 + row * 8 + 4);
#pragma unroll
    for (int j = 0; j < 4; ++j) {
      p[j] += a1a[j]; p[4 + j] += a1b[j];
      p[8 + j] += a2a[j]; p[12 + j] += a2b[j];
    }
  }
#pragma unroll
  for (int s = 1; s < 64; s <<= 1)
#pragma unroll
    for (int j = 0; j < 16; ++j) p[j] += __shfl_xor(p[j], s, 64);
  const int wid = tid >> 6;
  if ((tid & 63) == 0)
#pragma unroll
    for (int j = 0; j < 16; ++j) red[wid][j] = p[j];
  __syncthreads();
  if (tid < 16)
    sums[b * 16 + tid] = red[0][tid] + red[1][tid] + red[2][tid] + red[3][tid];
}

// ---------------------------------------------------------------------------
// Kernel 5: q1/q2 = value + adv - mean(adv). Output: [q1 | q2] fp32 flat.
// ---------------------------------------------------------------------------
__global__ void combine_kernel(const float* __restrict__ value, const float* __restrict__ adv1,
                               const float* __restrict__ adv2, const float* __restrict__ sums,
                               float* __restrict__ out) {
  const int idx = blockIdx.x * 256 + threadIdx.x;   // 0 .. 1048575
  const int half = 524288;
  const int which = (idx >= half) ? 1 : 0;
  const int rem = idx - which * half;
  const int b = rem >> 14;
  const int r2 = rem & 16383;
  const int n = r2 >> 3, j = r2 & 7;
  const long row = (long)b * 2048 + n;
  const float* adv = which ? adv2 : adv1;
  const float mean = sums[b * 16 + which * 8 + j] * (1.0f / 2048.0f);
  out[idx] = value[row] + adv[row * 8 + j] - mean;
}

// ---------------------------------------------------------------------------
extern "C" void kernel_launch(void* const* d_in, const int* in_sizes, int n_in,
                              void* d_out, int out_size, void* d_ws, size_t ws_size,
                              hipStream_t stream) {
  const float* x     = (const float*)d_in[0];
  const float* mask  = (const float*)d_in[1];
  const float* Wv    = (const float*)d_in[2];
  const float* bv    = (const float*)d_in[3];
  const float* Wk    = (const float*)d_in[4];
  const float* bk    = (const float*)d_in[5];
  const float* Wq    = (const float*)d_in[6];
  const float* bq    = (const float*)d_in[7];
  const float* Wout  = (const float*)d_in[8];
  const float* bout  = (const float*)d_in[9];
  const float* Wval  = (const float*)d_in[10];
  const float* bval  = (const float*)d_in[11];
  const float* Wadv1 = (const float*)d_in[12];
  const float* badv1 = (const float*)d_in[13];
  const float* Wadv2 = (const float*)d_in[14];
  const float* badv2 = (const float*)d_in[15];
  float* out = (float*)d_out;
  char* ws = (char*)d_ws;

  // workspace layout (bytes)
  unsigned short* q_bf   = (unsigned short*)(ws + 0);          // 16 MB
  unsigned short* Kf     = (unsigned short*)(ws + 16777216);   // 16 MB
  unsigned short* Vf     = (unsigned short*)(ws + 33554432);   // 16 MB
  unsigned short* out_at = (unsigned short*)(ws + 50331648);   // 16 MB
  float* value = (float*)(ws + 67108864);                      // 256 KB
  float* adv1  = (float*)(ws + 67371008);                      // 2 MB
  float* adv2  = (float*)(ws + 69468160);                      // 2 MB
  float* sums  = (float*)(ws + 71565312);                      // 2 KB
  unsigned short* Wf_hi = (unsigned short*)(ws + 71567360);    // 192 KB
  unsigned short* Wf_lo = (unsigned short*)(ws + 71763968);    // 192 KB
  unsigned short* WoutT = (unsigned short*)(ws + 71960576);    // 32 KB
  unsigned long long* bits = (unsigned long long*)(ws + 71993344);  // 16 MB

  prepack_kernel<<<2048, 256, 0, stream>>>(mask, bits);
  prep_kernel<<<112, 256, 0, stream>>>(Wv, Wk, Wq, Wout, Wf_hi, Wf_lo, WoutT);
  proj_kernel<<<512, 512, 0, stream>>>(x, Wf_hi, Wf_lo, bq, bk, bv, q_bf, Kf, Vf);
  attn_kernel<<<256, 512, 0, stream>>>(q_bf, Kf, Vf, bits, out_at);
  wout_heads_kernel<<<1024, 256, 0, stream>>>(out_at, WoutT, bout, Wval, bval,
                                              Wadv1, badv1, Wadv2, badv2,
                                              value, adv1, adv2);
  sums_kernel<<<32, 256, 0, stream>>>(adv1, adv2, sums);
  combine_kernel<<<4096, 256, 0, stream>>>(value, adv1, adv2, sums, out);
}

// Round 6
// 359.475 us; speedup vs baseline: 3.1661x; 1.0094x over previous
//
#include <hip/hip_runtime.h>
#include <hip/hip_bf16.h>

// BranchingQNetwork fused forward for MI355X (gfx950).
// B=32, N=2048, OBS=256, HID=128, n1=n2=8.
// v6: prepack vectorized (f32x4 + nibble OR-reduce, 4x fewer load instrs);
// attn single-barrier double-buffer (write-early) + setprio around MFMA.

typedef __attribute__((ext_vector_type(4))) float f32x4;
typedef __attribute__((ext_vector_type(8))) short bf16x8;
typedef __attribute__((ext_vector_type(4))) unsigned int u32x4;

#define LOG2E 1.44269504088896340736f
#define NEGC 9.0e15f

static __device__ __forceinline__ unsigned short f2bf(float f) {
  unsigned int x = __builtin_bit_cast(unsigned int, f);
  unsigned int r = (x + 0x7fffu + ((x >> 16) & 1u)) >> 16;   // RNE
  return (unsigned short)r;
}
static __device__ __forceinline__ float bf2f(unsigned short u) {
  return __builtin_bit_cast(float, ((unsigned int)u) << 16);
}
static __device__ __forceinline__ unsigned int pack2bf(float lo, float hi) {
  return (unsigned int)f2bf(lo) | ((unsigned int)f2bf(hi) << 16);
}
static __device__ __forceinline__ f32x4 mfma16(bf16x8 a, bf16x8 b, f32x4 c) {
  return __builtin_amdgcn_mfma_f32_16x16x32_bf16(a, b, c, 0, 0, 0);
}

// ---------------------------------------------------------------------------
// Kernel P: mask prepack. mask fp32 -> bitmask u64; bits[row*32+t] covers
// kv = t*64..t*64+63. Each lane loads f32x4 (1KB per wave instr, contiguous),
// builds a nibble, OR-reduces across 16-lane groups (4 shfl_xor) -> u64.
// ---------------------------------------------------------------------------
__global__ __launch_bounds__(256) void prepack_kernel(const float* __restrict__ mask,
                                                      unsigned long long* __restrict__ bits) {
  const int lane = threadIdx.x & 63;
  const int gwave = (blockIdx.x << 2) | (threadIdx.x >> 6);  // 8192 waves
  const int sub = lane & 15, grp = lane >> 4;
  for (int r = 0; r < 8; ++r) {
    const long row = (long)gwave * 8 + r;
    const float* mp = mask + row * 2048;
    unsigned long long* op = bits + row * 32;
#pragma unroll
    for (int g = 0; g < 8; ++g) {
      f32x4 v = *(const f32x4*)(mp + g * 256 + lane * 4);
      unsigned int nib = (v[0] != 0.f ? 1u : 0u) | (v[1] != 0.f ? 2u : 0u)
                       | (v[2] != 0.f ? 4u : 0u) | (v[3] != 0.f ? 8u : 0u);
      unsigned long long val = (unsigned long long)nib << (sub * 4);
      val |= __shfl_xor(val, 1, 64);
      val |= __shfl_xor(val, 2, 64);
      val |= __shfl_xor(val, 4, 64);
      val |= __shfl_xor(val, 8, 64);
      if (sub == 0) op[g * 4 + grp] = val;   // t = g*4 + grp
    }
  }
}

// ---------------------------------------------------------------------------
// Kernel 0: weight prep into FRAG-LINEAR layouts.
// Wf[(kc*24 + t)*64 + lane][e] = Wsec[k = kc*32 + (lane>>4)*8 + e]
//                                    [j = (t&7)*16 + (lane&15)]
// with sec = t>>3 (0=q,1=k,2=v). hi/lo split. WoutT unchanged ([j][k]).
// ---------------------------------------------------------------------------
__global__ __launch_bounds__(256) void prep_kernel(
    const float* __restrict__ Wv, const float* __restrict__ Wk,
    const float* __restrict__ Wq, const float* __restrict__ Wout,
    unsigned short* __restrict__ Wf_hi, unsigned short* __restrict__ Wf_lo,
    unsigned short* __restrict__ WoutT) {
  int gid = blockIdx.x * 256 + threadIdx.x;
  if (gid < 12288) {                 // (kc, t, lane)
    int kc = gid / 1536;
    int rem = gid - kc * 1536;
    int t = rem >> 6, lane = rem & 63;
    int hf = lane & 15, qf = lane >> 4;
    int sec = t >> 3;
    int j = (t & 7) * 16 + hf;
    const float* W = (sec == 0) ? Wq : (sec == 1) ? Wk : Wv;
#pragma unroll
    for (int e = 0; e < 8; ++e) {
      int k = kc * 32 + qf * 8 + e;
      float w = W[k * 128 + j];
      unsigned short hi = f2bf(w);
      Wf_hi[gid * 8 + e] = hi;
      Wf_lo[gid * 8 + e] = f2bf(w - bf2f(hi));
    }
  } else if (gid < 12288 + 16384) {
    int i2 = gid - 12288;
    int j = i2 >> 7, c = i2 & 127;
    WoutT[i2] = f2bf(Wout[c * 128 + j]);
  }
}

// ---------------------------------------------------------------------------
// Kernel 1: fused QKV projection. 512 threads (8 waves), 128 rows/block.
// W staged per-kc in LDS. 3-pass hi/lo x*W MFMA. Outputs via LDS vbuf:
//   q  -> row-major q_bf[row][128]
//   k  -> frag-linear Kf[(b*32+t)*16 + m*4+kc][lane][8]
//   v  -> frag-linear Vf[(b*32+t)*16 + ht*2+c][lane][8]   (V^T: [h][n])
// ---------------------------------------------------------------------------
__global__ __launch_bounds__(512, 2) void proj_kernel(
    const float* __restrict__ x,
    const unsigned short* __restrict__ Wf_hi, const unsigned short* __restrict__ Wf_lo,
    const float* __restrict__ bq, const float* __restrict__ bk, const float* __restrict__ bv,
    unsigned short* __restrict__ q_bf, unsigned short* __restrict__ Kf,
    unsigned short* __restrict__ Vf) {
  __shared__ bf16x8 wst_hi[1536];              // 24 KB
  __shared__ bf16x8 wst_lo[1536];              // 24 KB
  __shared__ unsigned short vbuf[128][136];    // 34.8 KB

  const int tid = threadIdx.x;
  const int lane = tid & 63, wid = tid >> 6;
  const int qq = lane >> 4, hh = lane & 15;
  const long rbase = (long)blockIdx.x * 128;
  const long rowA = rbase + wid * 16 + hh;
  const f32x4 zero4 = {0.f, 0.f, 0.f, 0.f};
  f32x4 acc[24];
#pragma unroll
  for (int t = 0; t < 24; ++t) acc[t] = zero4;

  for (int kc = 0; kc < 8; ++kc) {
    __syncthreads();
#pragma unroll
    for (int i = 0; i < 3; ++i) {
      int idx = i * 512 + tid;
      wst_hi[idx] = *(const bf16x8*)(Wf_hi + ((long)kc * 1536 + idx) * 8);
      wst_lo[idx] = *(const bf16x8*)(Wf_lo + ((long)kc * 1536 + idx) * 8);
    }
    __syncthreads();

    const float* xp = x + rowA * 256 + kc * 32 + qq * 8;
    f32x4 x0 = *(const f32x4*)xp;
    f32x4 x1 = *(const f32x4*)(xp + 4);
    bf16x8 ah, al;
#pragma unroll
    for (int j = 0; j < 8; ++j) {
      float f = (j < 4) ? x0[j] : x1[j - 4];
      unsigned short h = f2bf(f);
      ah[j] = (short)h;
      al[j] = (short)f2bf(f - bf2f(h));
    }
#pragma unroll
    for (int t = 0; t < 24; ++t) {
      bf16x8 bh = wst_hi[t * 64 + lane];
      bf16x8 bl = wst_lo[t * 64 + lane];
      acc[t] = mfma16(ah, bh, acc[t]);
      acc[t] = mfma16(al, bh, acc[t]);
      acc[t] = mfma16(ah, bl, acc[t]);
    }
  }

  const int rowL = wid * 16 + qq * 4;
  const int b = (int)(rbase >> 11);
  const int tbase = (int)((rbase & 2047) >> 6);   // 2 K/V tiles per block

  for (int sec = 0; sec < 3; ++sec) {
    __syncthreads();
#pragma unroll
    for (int tp = 0; tp < 8; ++tp) {
      const int t = sec * 8 + tp;
      const int j = tp * 16 + hh;
      const float bias = (sec == 0) ? bq[j] : (sec == 1) ? bk[j] : bv[j];
#pragma unroll
      for (int r = 0; r < 4; ++r) {
        unsigned short h = f2bf(fmaxf(acc[t][r] + bias, 0.f));
        if (sec == 2) vbuf[j][rowL + r] = h;       // V transposed: [h][n]
        else          vbuf[rowL + r][j] = h;
      }
    }
    __syncthreads();
    if (sec == 0) {
      const int row = tid >> 2, ch = tid & 3;
      bf16x8 w = *(const bf16x8*)&vbuf[row][ch * 32];
      bf16x8 w2 = *(const bf16x8*)&vbuf[row][ch * 32 + 8];
      bf16x8 w3 = *(const bf16x8*)&vbuf[row][ch * 32 + 16];
      bf16x8 w4 = *(const bf16x8*)&vbuf[row][ch * 32 + 24];
      unsigned short* op = q_bf + (rbase + row) * 128 + ch * 32;
      *(bf16x8*)op = w; *(bf16x8*)(op + 8) = w2;
      *(bf16x8*)(op + 16) = w3; *(bf16x8*)(op + 24) = w4;
    } else if (sec == 1) {
#pragma unroll
      for (int it = 0; it < 4; ++it) {
        int gid = it * 512 + tid;                    // (tt, m, kc, lane)
        int tt = gid >> 10, m = (gid >> 8) & 3, kc = (gid >> 6) & 3, ln = gid & 63;
        int hf = ln & 15, qf = ln >> 4;
        bf16x8 w = *(const bf16x8*)&vbuf[tt * 64 + m * 16 + hf][kc * 32 + qf * 8];
        long off = (((long)(b * 32 + tbase + tt) * 16 + m * 4 + kc) * 64 + ln) * 8;
        *(bf16x8*)(Kf + off) = w;
      }
    } else {
#pragma unroll
      for (int it = 0; it < 4; ++it) {
        int gid = it * 512 + tid;                    // (tt, ht, c, lane)
        int tt = gid >> 10, ht = (gid >> 7) & 7, c = (gid >> 6) & 1, ln = gid & 63;
        int hf = ln & 15, qf = ln >> 4;
        bf16x8 w = *(const bf16x8*)&vbuf[ht * 16 + hf][tt * 64 + c * 32 + qf * 8];
        long off = (((long)(b * 32 + tbase + tt) * 16 + ht * 2 + c) * 64 + ln) * 8;
        *(bf16x8*)(Vf + off) = w;
      }
    }
  }
}

// ---------------------------------------------------------------------------
// Kernel 2: flash attention, LDS-shared K/V, SINGLE barrier per tile.
// 256 blocks x 512 threads (8 waves x 32 q-rows), all kv per block.
// Per iter: WRITEBUF(next) || LOADREG(next+1) issued BEFORE compute(cur);
// one __syncthreads at iteration end orders buffer reuse. setprio around MFMA.
// ---------------------------------------------------------------------------
__global__ __launch_bounds__(512, 2) void attn_kernel(
    const unsigned short* __restrict__ q_bf, const unsigned short* __restrict__ Kf,
    const unsigned short* __restrict__ Vf,
    const unsigned long long* __restrict__ bits, unsigned short* __restrict__ out_att) {
  __shared__ bf16x8 kls[2][1024];   // 2 x 16 KB
  __shared__ bf16x8 vls[2][1024];   // 2 x 16 KB

  const int tid = threadIdx.x;
  const int lane = tid & 63, wid = tid >> 6;
  const int qq = lane >> 4, hh = lane & 15;
  const int orig = blockIdx.x;
  const int b = ((orig & 7) << 2) | ((orig >> 3) & 3);   // XCD-clustered batches
  const int nb = orig >> 5;
  const long qbase = (long)b * 2048 + nb * 256 + wid * 32;

  const f32x4 zero4 = {0.f, 0.f, 0.f, 0.f};

  bf16x8 qh[2][4];
#pragma unroll
  for (int ctq = 0; ctq < 2; ++ctq)
#pragma unroll
    for (int kc = 0; kc < 4; ++kc)
      qh[ctq][kc] = *(const bf16x8*)(q_bf + (qbase + ctq * 16 + hh) * 128 + kc * 32 + qq * 8);

  const unsigned long long* br0 = bits + (qbase + hh) * 32;
  const unsigned long long* br1 = bits + (qbase + 16 + hh) * 32;
  const unsigned short* kf0 = Kf + (long)(b * 32) * 8192;
  const unsigned short* vf0 = Vf + (long)(b * 32) * 8192;

  f32x4 o_acc[8][2];
#pragma unroll
  for (int ht = 0; ht < 8; ++ht) { o_acc[ht][0] = zero4; o_acc[ht][1] = zero4; }
  float m_run[2] = {-3.0e38f, -3.0e38f};
  float l_run[2] = {0.f, 0.f};

  bf16x8 stg[4];
  const int seg0 = wid * 4;
  auto LOADREG = [&](int t) {
#pragma unroll
    for (int i = 0; i < 4; ++i) {
      int seg = seg0 + i;
      const unsigned short* src = (seg < 16)
          ? kf0 + (long)t * 8192 + (seg * 64 + lane) * 8
          : vf0 + (long)t * 8192 + ((seg - 16) * 64 + lane) * 8;
      stg[i] = *(const bf16x8*)src;
    }
  };
  auto WRITEBUF = [&](int nb2) {
#pragma unroll
    for (int i = 0; i < 4; ++i) {
      int seg = seg0 + i;
      if (seg < 16) kls[nb2][seg * 64 + lane] = stg[i];
      else          vls[nb2][(seg - 16) * 64 + lane] = stg[i];
    }
  };

  LOADREG(0);
  WRITEBUF(0);
  LOADREG(1);
  __syncthreads();

  unsigned long long bc0 = br0[0];
  unsigned long long bc1 = br1[0];

  const int src0 = (((qq << 1)) & 3) * 16 + hh;
  const int src1 = (((qq << 1) + 1) & 3) * 16 + hh;
  const bool hiq = qq >= 2;
  int cur = 0;

  for (int t = 0; t < 32; ++t) {
    unsigned long long bn0 = 0, bn1 = 0;
    if (t + 1 < 32) { bn0 = br0[t + 1]; bn1 = br1[t + 1]; }

    // next-tile staging issued BEFORE compute: LDS writes of buf[cur^1]
    // overlap other waves' compute(t) on buf[cur]; global loads for t+2
    // stay in flight under compute(t).
    if (t + 1 < 32) WRITEBUF(cur ^ 1);
    if (t + 2 < 32) LOADREG(t + 2);

    // S^T = K·Q^T from LDS (conflict-free lane*16 reads)
    f32x4 s[2][4];
#pragma unroll
    for (int m = 0; m < 4; ++m) { s[0][m] = zero4; s[1][m] = zero4; }
    __builtin_amdgcn_s_setprio(1);
#pragma unroll
    for (int m = 0; m < 4; ++m) {
      bf16x8 khf[4];
#pragma unroll
      for (int kc = 0; kc < 4; ++kc) khf[kc] = kls[cur][(m * 4 + kc) * 64 + lane];
#pragma unroll
      for (int kc = 0; kc < 4; ++kc)
#pragma unroll
        for (int ctq = 0; ctq < 2; ++ctq)
          s[ctq][m] = mfma16(khf[kc], qh[ctq][kc], s[ctq][m]);
    }
    __builtin_amdgcn_s_setprio(0);

    // bitmask select
    {
      const unsigned long long bb0 = bc0 >> (qq * 4);
      const unsigned long long bb1 = bc1 >> (qq * 4);
#pragma unroll
      for (int m = 0; m < 4; ++m)
#pragma unroll
        for (int r = 0; r < 4; ++r) {
          const int sh = m * 16 + r;
          s[0][m][r] = ((bb0 >> sh) & 1ull) ? s[0][m][r] : -NEGC;
          s[1][m][r] = ((bb1 >> sh) & 1ull) ? s[1][m][r] : -NEGC;
        }
    }

    // fp32 online softmax with defer-max
    unsigned int pk[2][4][2];
#pragma unroll
    for (int ctq = 0; ctq < 2; ++ctq) {
      float mx = s[ctq][0][0];
#pragma unroll
      for (int m = 0; m < 4; ++m)
#pragma unroll
        for (int r = 0; r < 4; ++r) mx = fmaxf(mx, s[ctq][m][r]);
      mx = fmaxf(mx, __shfl_xor(mx, 16, 64));
      mx = fmaxf(mx, __shfl_xor(mx, 32, 64));
      if (__any(mx > m_run[ctq])) {
        float mnew = fmaxf(m_run[ctq], mx);
        float sc = exp2f((m_run[ctq] - mnew) * LOG2E);
        m_run[ctq] = mnew;
        l_run[ctq] *= sc;
#pragma unroll
        for (int ht = 0; ht < 8; ++ht) o_acc[ht][ctq] *= sc;
      }
      float ps = 0.f;
#pragma unroll
      for (int m = 0; m < 4; ++m)
#pragma unroll
        for (int r = 0; r < 4; ++r) {
          float p = exp2f((s[ctq][m][r] - m_run[ctq]) * LOG2E);
          s[ctq][m][r] = p;
          ps += p;
        }
      ps += __shfl_xor(ps, 16, 64);
      ps += __shfl_xor(ps, 32, 64);
      l_run[ctq] += ps;
#pragma unroll
      for (int m = 0; m < 4; ++m) {
        pk[ctq][m][0] = pack2bf(s[ctq][m][0], s[ctq][m][1]);
        pk[ctq][m][1] = pack2bf(s[ctq][m][2], s[ctq][m][3]);
      }
    }

    // redistribute P (C layout) -> B-frag layout via shfl
    bf16x8 pb[2][2];
#pragma unroll
    for (int ctq = 0; ctq < 2; ++ctq)
#pragma unroll
      for (int c = 0; c < 2; ++c) {
        unsigned int a0 = (unsigned int)__shfl((int)pk[ctq][2 * c][0], src0, 64);
        unsigned int a1 = (unsigned int)__shfl((int)pk[ctq][2 * c][1], src0, 64);
        unsigned int a2 = (unsigned int)__shfl((int)pk[ctq][2 * c][0], src1, 64);
        unsigned int a3 = (unsigned int)__shfl((int)pk[ctq][2 * c][1], src1, 64);
        unsigned int b0 = (unsigned int)__shfl((int)pk[ctq][2 * c + 1][0], src0, 64);
        unsigned int b1 = (unsigned int)__shfl((int)pk[ctq][2 * c + 1][1], src0, 64);
        unsigned int b2 = (unsigned int)__shfl((int)pk[ctq][2 * c + 1][0], src1, 64);
        unsigned int b3 = (unsigned int)__shfl((int)pk[ctq][2 * c + 1][1], src1, 64);
        u32x4 w;
        w[0] = hiq ? b0 : a0;
        w[1] = hiq ? b1 : a1;
        w[2] = hiq ? b2 : a2;
        w[3] = hiq ? b3 : a3;
        pb[ctq][c] = __builtin_bit_cast(bf16x8, w);
      }

    // O^T += V^T · P from LDS
    __builtin_amdgcn_s_setprio(1);
#pragma unroll
    for (int ht = 0; ht < 8; ++ht)
#pragma unroll
      for (int c = 0; c < 2; ++c) {
        bf16x8 vf = vls[cur][(ht * 2 + c) * 64 + lane];
#pragma unroll
        for (int ctq = 0; ctq < 2; ++ctq)
          o_acc[ht][ctq] = mfma16(vf, pb[ctq][c], o_acc[ht][ctq]);
      }
    __builtin_amdgcn_s_setprio(0);

    __syncthreads();   // single barrier: orders buf[cur^1] reads@t-1 vs writes@t
    cur ^= 1;
    bc0 = bn0;
    bc1 = bn1;
  }

  // epilogue: normalize, store bf16. O^T frag: row h = ht*16+qq*4+r, col q=hh.
#pragma unroll
  for (int ctq = 0; ctq < 2; ++ctq) {
    float inv = 1.0f / l_run[ctq];
    const long row = qbase + ctq * 16 + hh;
#pragma unroll
    for (int ht = 0; ht < 8; ++ht) {
      f32x4 o = o_acc[ht][ctq];
      uint2 w;
      w.x = pack2bf(o[0] * inv, o[1] * inv);
      w.y = pack2bf(o[2] * inv, o[3] * inv);
      *(uint2*)(out_att + row * 128 + ht * 16 + qq * 4) = w;
    }
  }
}

// ---------------------------------------------------------------------------
// Kernel 3: out = relu(out_att @ Wout + bout) fused with the three heads.
// ---------------------------------------------------------------------------
__global__ __launch_bounds__(256) void wout_heads_kernel(
    const unsigned short* __restrict__ out_att, const unsigned short* __restrict__ WoutT,
    const float* __restrict__ bout,
    const float* __restrict__ Wval, const float* __restrict__ bval,
    const float* __restrict__ Wadv1, const float* __restrict__ badv1,
    const float* __restrict__ Wadv2, const float* __restrict__ badv2,
    float* __restrict__ value, float* __restrict__ adv1, float* __restrict__ adv2) {
  const int lane = threadIdx.x & 63, wid = threadIdx.x >> 6;
  const int qq = lane >> 4, hh = lane & 15;
  const long rowA = (long)blockIdx.x * 64 + wid * 16 + hh;
  const f32x4 zero4 = {0.f, 0.f, 0.f, 0.f};
  f32x4 acc[8];
#pragma unroll
  for (int t = 0; t < 8; ++t) acc[t] = zero4;
#pragma unroll
  for (int kc = 0; kc < 4; ++kc) {
    bf16x8 af = *(const bf16x8*)(out_att + rowA * 128 + kc * 32 + qq * 8);
#pragma unroll
    for (int t = 0; t < 8; ++t) {
      bf16x8 bf = *(const bf16x8*)(WoutT + (t * 16 + hh) * 128 + kc * 32 + qq * 8);
      acc[t] = mfma16(af, bf, acc[t]);
    }
  }
  float pv[4] = {0.f, 0.f, 0.f, 0.f};
  float pa1[4][8], pa2[4][8];
#pragma unroll
  for (int r = 0; r < 4; ++r)
#pragma unroll
    for (int j = 0; j < 8; ++j) { pa1[r][j] = 0.f; pa2[r][j] = 0.f; }
#pragma unroll
  for (int t = 0; t < 8; ++t) {
    const int col = t * 16 + hh;
    const float bo = bout[col];
    const float wv = Wval[col];
    const f32x4 w1a = *(const f32x4*)(Wadv1 + col * 8);
    const f32x4 w1b = *(const f32x4*)(Wadv1 + col * 8 + 4);
    const f32x4 w2a = *(const f32x4*)(Wadv2 + col * 8);
    const f32x4 w2b = *(const f32x4*)(Wadv2 + col * 8 + 4);
#pragma unroll
    for (int r = 0; r < 4; ++r) {
      float h = fmaxf(acc[t][r] + bo, 0.f);
      pv[r] += h * wv;
#pragma unroll
      for (int j = 0; j < 4; ++j) {
        pa1[r][j]     += h * w1a[j];
        pa1[r][4 + j] += h * w1b[j];
        pa2[r][j]     += h * w2a[j];
        pa2[r][4 + j] += h * w2b[j];
      }
    }
  }
#pragma unroll
  for (int r = 0; r < 4; ++r) {
#pragma unroll
    for (int s = 1; s < 16; s <<= 1) {
      pv[r] += __shfl_xor(pv[r], s, 64);
#pragma unroll
      for (int j = 0; j < 8; ++j) {
        pa1[r][j] += __shfl_xor(pa1[r][j], s, 64);
        pa2[r][j] += __shfl_xor(pa2[r][j], s, 64);
      }
    }
  }
  if (hh == 0) {
    const float bv0 = bval[0];
#pragma unroll
    for (int r = 0; r < 4; ++r) {
      const long row = (long)blockIdx.x * 64 + wid * 16 + qq * 4 + r;
      value[row] = pv[r] + bv0;
#pragma unroll
      for (int j = 0; j < 8; ++j) {
        adv1[row * 8 + j] = pa1[r][j] + badv1[j];
        adv2[row * 8 + j] = pa2[r][j] + badv2[j];
      }
    }
  }
}

// ---------------------------------------------------------------------------
// Kernel 4: per-batch column sums of adv1/adv2 over N (deterministic tree).
// ---------------------------------------------------------------------------
__global__ __launch_bounds__(256) void sums_kernel(const float* __restrict__ adv1,
                                                   const float* __restrict__ adv2,
                                                   float* __restrict__ sums) {
  const int b = blockIdx.x, tid = threadIdx.x;
  __shared__ float red[4][16];
  float p[16];
#pragma unroll
  for (int j = 0; j < 16; ++j) p[j] = 0.f;
  for (int n = tid; n < 2048; n += 256) {
    const long row = (long)b * 2048 + n;
    const f32x4 a1a = *(const f32x4*)(adv1 + row * 8);
    const f32x4 a1b = *(const f32x4*)(adv1 + row * 8 + 4);
    const f32x4 a2a = *(const f32x4*)(adv2 + row * 8);
    const f32x4 a2b = *(const f32x4*)(adv2 + row * 8 + 4);
#pragma unroll
    for (int j = 0; j < 4; ++j) {
      p[j] += a1a[j]; p[4 + j] += a1b[j];
      p[8 + j] += a2a[j]; p[12 + j] += a2b[j];
    }
  }
#pragma unroll
  for (int s = 1; s < 64; s <<= 1)
#pragma unroll
    for (int j = 0; j < 16; ++j) p[j] += __shfl_xor(p[j], s, 64);
  const int wid = tid >> 6;
  if ((tid & 63) == 0)
#pragma unroll
    for (int j = 0; j < 16; ++j) red[wid][j] = p[j];
  __syncthreads();
  if (tid < 16)
    sums[b * 16 + tid] = red[0][tid] + red[1][tid] + red[2][tid] + red[3][tid];
}

// ---------------------------------------------------------------------------
// Kernel 5: q1/q2 = value + adv - mean(adv). Output: [q1 | q2] fp32 flat.
// ---------------------------------------------------------------------------
__global__ void combine_kernel(const float* __restrict__ value, const float* __restrict__ adv1,
                               const float* __restrict__ adv2, const float* __restrict__ sums,
                               float* __restrict__ out) {
  const int idx = blockIdx.x * 256 + threadIdx.x;   // 0 .. 1048575
  const int half = 524288;
  const int which = (idx >= half) ? 1 : 0;
  const int rem = idx - which * half;
  const int b = rem >> 14;
  const int r2 = rem & 16383;
  const int n = r2 >> 3, j = r2 & 7;
  const long row = (long)b * 2048 + n;
  const float* adv = which ? adv2 : adv1;
  const float mean = sums[b * 16 + which * 8 + j] * (1.0f / 2048.0f);
  out[idx] = value[row] + adv[row * 8 + j] - mean;
}

// ---------------------------------------------------------------------------
extern "C" void kernel_launch(void* const* d_in, const int* in_sizes, int n_in,
                              void* d_out, int out_size, void* d_ws, size_t ws_size,
                              hipStream_t stream) {
  const float* x     = (const float*)d_in[0];
  const float* mask  = (const float*)d_in[1];
  const float* Wv    = (const float*)d_in[2];
  const float* bv    = (const float*)d_in[3];
  const float* Wk    = (const float*)d_in[4];
  const float* bk    = (const float*)d_in[5];
  const float* Wq    = (const float*)d_in[6];
  const float* bq    = (const float*)d_in[7];
  const float* Wout  = (const float*)d_in[8];
  const float* bout  = (const float*)d_in[9];
  const float* Wval  = (const float*)d_in[10];
  const float* bval  = (const float*)d_in[11];
  const float* Wadv1 = (const float*)d_in[12];
  const float* badv1 = (const float*)d_in[13];
  const float* Wadv2 = (const float*)d_in[14];
  const float* badv2 = (const float*)d_in[15];
  float* out = (float*)d_out;
  char* ws = (char*)d_ws;

  // workspace layout (bytes)
  unsigned short* q_bf   = (unsigned short*)(ws + 0);          // 16 MB
  unsigned short* Kf     = (unsigned short*)(ws + 16777216);   // 16 MB
  unsigned short* Vf     = (unsigned short*)(ws + 33554432);   // 16 MB
  unsigned short* out_at = (unsigned short*)(ws + 50331648);   // 16 MB
  float* value = (float*)(ws + 67108864);                      // 256 KB
  float* adv1  = (float*)(ws + 67371008);                      // 2 MB
  float* adv2  = (float*)(ws + 69468160);                      // 2 MB
  float* sums  = (float*)(ws + 71565312);                      // 2 KB
  unsigned short* Wf_hi = (unsigned short*)(ws + 71567360);    // 192 KB
  unsigned short* Wf_lo = (unsigned short*)(ws + 71763968);    // 192 KB
  unsigned short* WoutT = (unsigned short*)(ws + 71960576);    // 32 KB
  unsigned long long* bits = (unsigned long long*)(ws + 71993344);  // 16 MB

  prepack_kernel<<<2048, 256, 0, stream>>>(mask, bits);
  prep_kernel<<<112, 256, 0, stream>>>(Wv, Wk, Wq, Wout, Wf_hi, Wf_lo, WoutT);
  proj_kernel<<<512, 512, 0, stream>>>(x, Wf_hi, Wf_lo, bq, bk, bv, q_bf, Kf, Vf);
  attn_kernel<<<256, 512, 0, stream>>>(q_bf, Kf, Vf, bits, out_at);
  wout_heads_kernel<<<1024, 256, 0, stream>>>(out_at, WoutT, bout, Wval, bval,
                                              Wadv1, badv1, Wadv2, badv2,
                                              value, adv1, adv2);
  sums_kernel<<<32, 256, 0, stream>>>(adv1, adv2, sums);
  combine_kernel<<<4096, 256, 0, stream>>>(value, adv1, adv2, sums, out);
}

// Round 7
// 348.947 us; speedup vs baseline: 3.2616x; 1.0302x over previous
//
#include <hip/hip_runtime.h>
#include <hip/hip_bf16.h>

// BranchingQNetwork fused forward for MI355X (gfx950).
// B=32, N=2048, OBS=256, HID=128, n1=n2=8.
// v7: prepack uses ballot-based bit assembly (no cross-lane shuffles);
// attn re-parameterized to 512 blocks x 4 waves -> 2 barrier domains/CU;
// threshold defer-max (THR=8).

typedef __attribute__((ext_vector_type(4))) float f32x4;
typedef __attribute__((ext_vector_type(8))) short bf16x8;
typedef __attribute__((ext_vector_type(4))) unsigned int u32x4;

#define LOG2E 1.44269504088896340736f
#define NEGC 9.0e15f

static __device__ __forceinline__ unsigned short f2bf(float f) {
  unsigned int x = __builtin_bit_cast(unsigned int, f);
  unsigned int r = (x + 0x7fffu + ((x >> 16) & 1u)) >> 16;   // RNE
  return (unsigned short)r;
}
static __device__ __forceinline__ float bf2f(unsigned short u) {
  return __builtin_bit_cast(float, ((unsigned int)u) << 16);
}
static __device__ __forceinline__ unsigned int pack2bf(float lo, float hi) {
  return (unsigned int)f2bf(lo) | ((unsigned int)f2bf(hi) << 16);
}
static __device__ __forceinline__ f32x4 mfma16(bf16x8 a, bf16x8 b, f32x4 c) {
  return __builtin_amdgcn_mfma_f32_16x16x32_bf16(a, b, c, 0, 0, 0);
}

// ---------------------------------------------------------------------------
// Kernel P: mask prepack. mask fp32 -> bitmask u64; word bits[row*32 + T]
// covers kv = T*64..T*64+63 with PERMUTED layout: bit (j*16 + u) = kv (4u+j).
// Per 256-float group: 1 f32x4 load/lane (1KB/wave, row-sequential stream),
// 4 ballots, per-lane 64-bit extract; lanes 0-3 store the 4 tile words.
// No cross-lane shuffles at all.
// ---------------------------------------------------------------------------
__global__ __launch_bounds__(256) void prepack_kernel(const float* __restrict__ mask,
                                                      unsigned long long* __restrict__ bits) {
  const int lane = threadIdx.x & 63;
  const int gwave = (blockIdx.x << 2) | (threadIdx.x >> 6);  // 8192 waves
  const int T = lane & 3;
  const int sh = T << 4;                                     // 16*T
  for (int r = 0; r < 8; ++r) {
    const long row = (long)gwave * 8 + r;
    const float* mp = mask + row * 2048;
    unsigned long long* op = bits + row * 32;
#pragma unroll
    for (int g = 0; g < 8; ++g) {
      f32x4 v = *(const f32x4*)(mp + g * 256 + lane * 4);
      unsigned long long b0 = __ballot(v[0] != 0.0f);
      unsigned long long b1 = __ballot(v[1] != 0.0f);
      unsigned long long b2 = __ballot(v[2] != 0.0f);
      unsigned long long b3 = __ballot(v[3] != 0.0f);
      unsigned long long f0 = (b0 >> sh) & 0xFFFFull;
      unsigned long long f1 = (b1 >> sh) & 0xFFFFull;
      unsigned long long f2 = (b2 >> sh) & 0xFFFFull;
      unsigned long long f3 = (b3 >> sh) & 0xFFFFull;
      unsigned long long val = f0 | (f1 << 16) | (f2 << 32) | (f3 << 48);
      if (lane < 4) op[g * 4 + T] = val;
    }
  }
}

// ---------------------------------------------------------------------------
// Kernel 0: weight prep into FRAG-LINEAR layouts.
// Wf[(kc*24 + t)*64 + lane][e] = Wsec[k = kc*32 + (lane>>4)*8 + e]
//                                    [j = (t&7)*16 + (lane&15)]
// with sec = t>>3 (0=q,1=k,2=v). hi/lo split. WoutT unchanged ([j][k]).
// ---------------------------------------------------------------------------
__global__ __launch_bounds__(256) void prep_kernel(
    const float* __restrict__ Wv, const float* __restrict__ Wk,
    const float* __restrict__ Wq, const float* __restrict__ Wout,
    unsigned short* __restrict__ Wf_hi, unsigned short* __restrict__ Wf_lo,
    unsigned short* __restrict__ WoutT) {
  int gid = blockIdx.x * 256 + threadIdx.x;
  if (gid < 12288) {                 // (kc, t, lane)
    int kc = gid / 1536;
    int rem = gid - kc * 1536;
    int t = rem >> 6, lane = rem & 63;
    int hf = lane & 15, qf = lane >> 4;
    int sec = t >> 3;
    int j = (t & 7) * 16 + hf;
    const float* W = (sec == 0) ? Wq : (sec == 1) ? Wk : Wv;
#pragma unroll
    for (int e = 0; e < 8; ++e) {
      int k = kc * 32 + qf * 8 + e;
      float w = W[k * 128 + j];
      unsigned short hi = f2bf(w);
      Wf_hi[gid * 8 + e] = hi;
      Wf_lo[gid * 8 + e] = f2bf(w - bf2f(hi));
    }
  } else if (gid < 12288 + 16384) {
    int i2 = gid - 12288;
    int j = i2 >> 7, c = i2 & 127;
    WoutT[i2] = f2bf(Wout[c * 128 + j]);
  }
}

// ---------------------------------------------------------------------------
// Kernel 1: fused QKV projection. 512 threads (8 waves), 128 rows/block.
// W staged per-kc in LDS. 3-pass hi/lo x*W MFMA. Outputs via LDS vbuf:
//   q  -> row-major q_bf[row][128]
//   k  -> frag-linear Kf[(b*32+t)*16 + m*4+kc][lane][8]
//   v  -> frag-linear Vf[(b*32+t)*16 + ht*2+c][lane][8]   (V^T: [h][n])
// ---------------------------------------------------------------------------
__global__ __launch_bounds__(512, 2) void proj_kernel(
    const float* __restrict__ x,
    const unsigned short* __restrict__ Wf_hi, const unsigned short* __restrict__ Wf_lo,
    const float* __restrict__ bq, const float* __restrict__ bk, const float* __restrict__ bv,
    unsigned short* __restrict__ q_bf, unsigned short* __restrict__ Kf,
    unsigned short* __restrict__ Vf) {
  __shared__ bf16x8 wst_hi[1536];              // 24 KB
  __shared__ bf16x8 wst_lo[1536];              // 24 KB
  __shared__ unsigned short vbuf[128][136];    // 34.8 KB

  const int tid = threadIdx.x;
  const int lane = tid & 63, wid = tid >> 6;
  const int qq = lane >> 4, hh = lane & 15;
  const long rbase = (long)blockIdx.x * 128;
  const long rowA = rbase + wid * 16 + hh;
  const f32x4 zero4 = {0.f, 0.f, 0.f, 0.f};
  f32x4 acc[24];
#pragma unroll
  for (int t = 0; t < 24; ++t) acc[t] = zero4;

  for (int kc = 0; kc < 8; ++kc) {
    __syncthreads();
#pragma unroll
    for (int i = 0; i < 3; ++i) {
      int idx = i * 512 + tid;
      wst_hi[idx] = *(const bf16x8*)(Wf_hi + ((long)kc * 1536 + idx) * 8);
      wst_lo[idx] = *(const bf16x8*)(Wf_lo + ((long)kc * 1536 + idx) * 8);
    }
    __syncthreads();

    const float* xp = x + rowA * 256 + kc * 32 + qq * 8;
    f32x4 x0 = *(const f32x4*)xp;
    f32x4 x1 = *(const f32x4*)(xp + 4);
    bf16x8 ah, al;
#pragma unroll
    for (int j = 0; j < 8; ++j) {
      float f = (j < 4) ? x0[j] : x1[j - 4];
      unsigned short h = f2bf(f);
      ah[j] = (short)h;
      al[j] = (short)f2bf(f - bf2f(h));
    }
#pragma unroll
    for (int t = 0; t < 24; ++t) {
      bf16x8 bh = wst_hi[t * 64 + lane];
      bf16x8 bl = wst_lo[t * 64 + lane];
      acc[t] = mfma16(ah, bh, acc[t]);
      acc[t] = mfma16(al, bh, acc[t]);
      acc[t] = mfma16(ah, bl, acc[t]);
    }
  }

  const int rowL = wid * 16 + qq * 4;
  const int b = (int)(rbase >> 11);
  const int tbase = (int)((rbase & 2047) >> 6);   // 2 K/V tiles per block

  for (int sec = 0; sec < 3; ++sec) {
    __syncthreads();
#pragma unroll
    for (int tp = 0; tp < 8; ++tp) {
      const int t = sec * 8 + tp;
      const int j = tp * 16 + hh;
      const float bias = (sec == 0) ? bq[j] : (sec == 1) ? bk[j] : bv[j];
#pragma unroll
      for (int r = 0; r < 4; ++r) {
        unsigned short h = f2bf(fmaxf(acc[t][r] + bias, 0.f));
        if (sec == 2) vbuf[j][rowL + r] = h;       // V transposed: [h][n]
        else          vbuf[rowL + r][j] = h;
      }
    }
    __syncthreads();
    if (sec == 0) {
      const int row = tid >> 2, ch = tid & 3;
      bf16x8 w = *(const bf16x8*)&vbuf[row][ch * 32];
      bf16x8 w2 = *(const bf16x8*)&vbuf[row][ch * 32 + 8];
      bf16x8 w3 = *(const bf16x8*)&vbuf[row][ch * 32 + 16];
      bf16x8 w4 = *(const bf16x8*)&vbuf[row][ch * 32 + 24];
      unsigned short* op = q_bf + (rbase + row) * 128 + ch * 32;
      *(bf16x8*)op = w; *(bf16x8*)(op + 8) = w2;
      *(bf16x8*)(op + 16) = w3; *(bf16x8*)(op + 24) = w4;
    } else if (sec == 1) {
#pragma unroll
      for (int it = 0; it < 4; ++it) {
        int gid = it * 512 + tid;                    // (tt, m, kc, lane)
        int tt = gid >> 10, m = (gid >> 8) & 3, kc = (gid >> 6) & 3, ln = gid & 63;
        int hf = ln & 15, qf = ln >> 4;
        bf16x8 w = *(const bf16x8*)&vbuf[tt * 64 + m * 16 + hf][kc * 32 + qf * 8];
        long off = (((long)(b * 32 + tbase + tt) * 16 + m * 4 + kc) * 64 + ln) * 8;
        *(bf16x8*)(Kf + off) = w;
      }
    } else {
#pragma unroll
      for (int it = 0; it < 4; ++it) {
        int gid = it * 512 + tid;                    // (tt, ht, c, lane)
        int tt = gid >> 10, ht = (gid >> 7) & 7, c = (gid >> 6) & 1, ln = gid & 63;
        int hf = ln & 15, qf = ln >> 4;
        bf16x8 w = *(const bf16x8*)&vbuf[ht * 16 + hf][tt * 64 + c * 32 + qf * 8];
        long off = (((long)(b * 32 + tbase + tt) * 16 + ht * 2 + c) * 64 + ln) * 8;
        *(bf16x8*)(Vf + off) = w;
      }
    }
  }
}

// ---------------------------------------------------------------------------
// Kernel 2: flash attention, LDS-shared K/V, 2 blocks/CU (2 barrier domains).
// 512 blocks x 256 threads (4 waves x 32 q-rows = 128 rows/block), all kv.
// Single barrier/tile, write-early double-buffer, setprio, threshold
// defer-max (THR=8, exact math). Bit layout: bit(r*16+m*4+qq) after >>qq.
// ---------------------------------------------------------------------------
__global__ __launch_bounds__(256, 2) void attn_kernel(
    const unsigned short* __restrict__ q_bf, const unsigned short* __restrict__ Kf,
    const unsigned short* __restrict__ Vf,
    const unsigned long long* __restrict__ bits, unsigned short* __restrict__ out_att) {
  __shared__ bf16x8 kls[2][1024];   // 2 x 16 KB
  __shared__ bf16x8 vls[2][1024];   // 2 x 16 KB

  const int tid = threadIdx.x;
  const int lane = tid & 63, wid = tid >> 6;
  const int qq = lane >> 4, hh = lane & 15;
  const int orig = blockIdx.x;
  const int b = ((orig & 7) << 2) | ((orig >> 3) & 3);   // XCD-clustered batches
  const int nb = orig >> 5;                              // 0..15
  const long qbase = (long)b * 2048 + nb * 128 + wid * 32;

  const f32x4 zero4 = {0.f, 0.f, 0.f, 0.f};

  bf16x8 qh[2][4];
#pragma unroll
  for (int ctq = 0; ctq < 2; ++ctq)
#pragma unroll
    for (int kc = 0; kc < 4; ++kc)
      qh[ctq][kc] = *(const bf16x8*)(q_bf + (qbase + ctq * 16 + hh) * 128 + kc * 32 + qq * 8);

  const unsigned long long* br0 = bits + (qbase + hh) * 32;
  const unsigned long long* br1 = bits + (qbase + 16 + hh) * 32;
  const unsigned short* kf0 = Kf + (long)(b * 32) * 8192;
  const unsigned short* vf0 = Vf + (long)(b * 32) * 8192;

  f32x4 o_acc[8][2];
#pragma unroll
  for (int ht = 0; ht < 8; ++ht) { o_acc[ht][0] = zero4; o_acc[ht][1] = zero4; }
  float m_run[2] = {-3.0e38f, -3.0e38f};
  float l_run[2] = {0.f, 0.f};

  // staging: wave wid owns segments wid*8 .. wid*8+7 (seg<16: K, else V)
  bf16x8 stg[8];
  const int seg0 = wid * 8;
  auto LOADREG = [&](int t) {
#pragma unroll
    for (int i = 0; i < 8; ++i) {
      int seg = seg0 + i;
      const unsigned short* src = (seg < 16)
          ? kf0 + (long)t * 8192 + (seg * 64 + lane) * 8
          : vf0 + (long)t * 8192 + ((seg - 16) * 64 + lane) * 8;
      stg[i] = *(const bf16x8*)src;
    }
  };
  auto WRITEBUF = [&](int nb2) {
#pragma unroll
    for (int i = 0; i < 8; ++i) {
      int seg = seg0 + i;
      if (seg < 16) kls[nb2][seg * 64 + lane] = stg[i];
      else          vls[nb2][(seg - 16) * 64 + lane] = stg[i];
    }
  };

  LOADREG(0);
  WRITEBUF(0);
  LOADREG(1);
  __syncthreads();

  unsigned long long bc0 = br0[0];
  unsigned long long bc1 = br1[0];

  const int src0 = (((qq << 1)) & 3) * 16 + hh;
  const int src1 = (((qq << 1) + 1) & 3) * 16 + hh;
  const bool hiq = qq >= 2;
  int cur = 0;

  for (int t = 0; t < 32; ++t) {
    unsigned long long bn0 = 0, bn1 = 0;
    if (t + 1 < 32) { bn0 = br0[t + 1]; bn1 = br1[t + 1]; }

    // next-tile staging issued BEFORE compute
    if (t + 1 < 32) WRITEBUF(cur ^ 1);
    if (t + 2 < 32) LOADREG(t + 2);

    // S^T = K·Q^T from LDS (conflict-free lane*16 reads)
    f32x4 s[2][4];
#pragma unroll
    for (int m = 0; m < 4; ++m) { s[0][m] = zero4; s[1][m] = zero4; }
    __builtin_amdgcn_s_setprio(1);
#pragma unroll
    for (int m = 0; m < 4; ++m) {
      bf16x8 khf[4];
#pragma unroll
      for (int kc = 0; kc < 4; ++kc) khf[kc] = kls[cur][(m * 4 + kc) * 64 + lane];
#pragma unroll
      for (int kc = 0; kc < 4; ++kc)
#pragma unroll
        for (int ctq = 0; ctq < 2; ++ctq)
          s[ctq][m] = mfma16(khf[kc], qh[ctq][kc], s[ctq][m]);
    }
    __builtin_amdgcn_s_setprio(0);

    // bitmask select; bit layout: (bc >> qq) bit (r*16 + m*4)
    {
      const unsigned long long bb0 = bc0 >> qq;
      const unsigned long long bb1 = bc1 >> qq;
#pragma unroll
      for (int m = 0; m < 4; ++m)
#pragma unroll
        for (int r = 0; r < 4; ++r) {
          const int sh = r * 16 + m * 4;
          s[0][m][r] = ((bb0 >> sh) & 1ull) ? s[0][m][r] : -NEGC;
          s[1][m][r] = ((bb1 >> sh) & 1ull) ? s[1][m][r] : -NEGC;
        }
    }

    // fp32 online softmax, threshold defer-max (exact: P <= e^8)
    unsigned int pk[2][4][2];
#pragma unroll
    for (int ctq = 0; ctq < 2; ++ctq) {
      float mx = s[ctq][0][0];
#pragma unroll
      for (int m = 0; m < 4; ++m)
#pragma unroll
        for (int r = 0; r < 4; ++r) mx = fmaxf(mx, s[ctq][m][r]);
      mx = fmaxf(mx, __shfl_xor(mx, 16, 64));
      mx = fmaxf(mx, __shfl_xor(mx, 32, 64));
      if (__any(mx > m_run[ctq] + 8.0f)) {
        float mnew = fmaxf(m_run[ctq], mx);
        float sc = exp2f((m_run[ctq] - mnew) * LOG2E);
        m_run[ctq] = mnew;
        l_run[ctq] *= sc;
#pragma unroll
        for (int ht = 0; ht < 8; ++ht) o_acc[ht][ctq] *= sc;
      }
      float ps = 0.f;
#pragma unroll
      for (int m = 0; m < 4; ++m)
#pragma unroll
        for (int r = 0; r < 4; ++r) {
          float p = exp2f((s[ctq][m][r] - m_run[ctq]) * LOG2E);
          s[ctq][m][r] = p;
          ps += p;
        }
      ps += __shfl_xor(ps, 16, 64);
      ps += __shfl_xor(ps, 32, 64);
      l_run[ctq] += ps;
#pragma unroll
      for (int m = 0; m < 4; ++m) {
        pk[ctq][m][0] = pack2bf(s[ctq][m][0], s[ctq][m][1]);
        pk[ctq][m][1] = pack2bf(s[ctq][m][2], s[ctq][m][3]);
      }
    }

    // redistribute P (C layout) -> B-frag layout via shfl
    bf16x8 pb[2][2];
#pragma unroll
    for (int ctq = 0; ctq < 2; ++ctq)
#pragma unroll
      for (int c = 0; c < 2; ++c) {
        unsigned int a0 = (unsigned int)__shfl((int)pk[ctq][2 * c][0], src0, 64);
        unsigned int a1 = (unsigned int)__shfl((int)pk[ctq][2 * c][1], src0, 64);
        unsigned int a2 = (unsigned int)__shfl((int)pk[ctq][2 * c][0], src1, 64);
        unsigned int a3 = (unsigned int)__shfl((int)pk[ctq][2 * c][1], src1, 64);
        unsigned int b0 = (unsigned int)__shfl((int)pk[ctq][2 * c + 1][0], src0, 64);
        unsigned int b1 = (unsigned int)__shfl((int)pk[ctq][2 * c + 1][1], src0, 64);
        unsigned int b2 = (unsigned int)__shfl((int)pk[ctq][2 * c + 1][0], src1, 64);
        unsigned int b3 = (unsigned int)__shfl((int)pk[ctq][2 * c + 1][1], src1, 64);
        u32x4 w;
        w[0] = hiq ? b0 : a0;
        w[1] = hiq ? b1 : a1;
        w[2] = hiq ? b2 : a2;
        w[3] = hiq ? b3 : a3;
        pb[ctq][c] = __builtin_bit_cast(bf16x8, w);
      }

    // O^T += V^T · P from LDS
    __builtin_amdgcn_s_setprio(1);
#pragma unroll
    for (int ht = 0; ht < 8; ++ht)
#pragma unroll
      for (int c = 0; c < 2; ++c) {
        bf16x8 vf = vls[cur][(ht * 2 + c) * 64 + lane];
#pragma unroll
        for (int ctq = 0; ctq < 2; ++ctq)
          o_acc[ht][ctq] = mfma16(vf, pb[ctq][c], o_acc[ht][ctq]);
      }
    __builtin_amdgcn_s_setprio(0);

    __syncthreads();   // single barrier per tile
    cur ^= 1;
    bc0 = bn0;
    bc1 = bn1;
  }

  // epilogue: normalize, store bf16. O^T frag: row h = ht*16+qq*4+r, col q=hh.
#pragma unroll
  for (int ctq = 0; ctq < 2; ++ctq) {
    float inv = 1.0f / l_run[ctq];
    const long row = qbase + ctq * 16 + hh;
#pragma unroll
    for (int ht = 0; ht < 8; ++ht) {
      f32x4 o = o_acc[ht][ctq];
      uint2 w;
      w.x = pack2bf(o[0] * inv, o[1] * inv);
      w.y = pack2bf(o[2] * inv, o[3] * inv);
      *(uint2*)(out_att + row * 128 + ht * 16 + qq * 4) = w;
    }
  }
}

// ---------------------------------------------------------------------------
// Kernel 3: out = relu(out_att @ Wout + bout) fused with the three heads.
// ---------------------------------------------------------------------------
__global__ __launch_bounds__(256) void wout_heads_kernel(
    const unsigned short* __restrict__ out_att, const unsigned short* __restrict__ WoutT,
    const float* __restrict__ bout,
    const float* __restrict__ Wval, const float* __restrict__ bval,
    const float* __restrict__ Wadv1, const float* __restrict__ badv1,
    const float* __restrict__ Wadv2, const float* __restrict__ badv2,
    float* __restrict__ value, float* __restrict__ adv1, float* __restrict__ adv2) {
  const int lane = threadIdx.x & 63, wid = threadIdx.x >> 6;
  const int qq = lane >> 4, hh = lane & 15;
  const long rowA = (long)blockIdx.x * 64 + wid * 16 + hh;
  const f32x4 zero4 = {0.f, 0.f, 0.f, 0.f};
  f32x4 acc[8];
#pragma unroll
  for (int t = 0; t < 8; ++t) acc[t] = zero4;
#pragma unroll
  for (int kc = 0; kc < 4; ++kc) {
    bf16x8 af = *(const bf16x8*)(out_att + rowA * 128 + kc * 32 + qq * 8);
#pragma unroll
    for (int t = 0; t < 8; ++t) {
      bf16x8 bf = *(const bf16x8*)(WoutT + (t * 16 + hh) * 128 + kc * 32 + qq * 8);
      acc[t] = mfma16(af, bf, acc[t]);
    }
  }
  float pv[4] = {0.f, 0.f, 0.f, 0.f};
  float pa1[4][8], pa2[4][8];
#pragma unroll
  for (int r = 0; r < 4; ++r)
#pragma unroll
    for (int j = 0; j < 8; ++j) { pa1[r][j] = 0.f; pa2[r][j] = 0.f; }
#pragma unroll
  for (int t = 0; t < 8; ++t) {
    const int col = t * 16 + hh;
    const float bo = bout[col];
    const float wv = Wval[col];
    const f32x4 w1a = *(const f32x4*)(Wadv1 + col * 8);
    const f32x4 w1b = *(const f32x4*)(Wadv1 + col * 8 + 4);
    const f32x4 w2a = *(const f32x4*)(Wadv2 + col * 8);
    const f32x4 w2b = *(const f32x4*)(Wadv2 + col * 8 + 4);
#pragma unroll
    for (int r = 0; r < 4; ++r) {
      float h = fmaxf(acc[t][r] + bo, 0.f);
      pv[r] += h * wv;
#pragma unroll
      for (int j = 0; j < 4; ++j) {
        pa1[r][j]     += h * w1a[j];
        pa1[r][4 + j] += h * w1b[j];
        pa2[r][j]     += h * w2a[j];
        pa2[r][4 + j] += h * w2b[j];
      }
    }
  }
#pragma unroll
  for (int r = 0; r < 4; ++r) {
#pragma unroll
    for (int s = 1; s < 16; s <<= 1) {
      pv[r] += __shfl_xor(pv[r], s, 64);
#pragma unroll
      for (int j = 0; j < 8; ++j) {
        pa1[r][j] += __shfl_xor(pa1[r][j], s, 64);
        pa2[r][j] += __shfl_xor(pa2[r][j], s, 64);
      }
    }
  }
  if (hh == 0) {
    const float bv0 = bval[0];
#pragma unroll
    for (int r = 0; r < 4; ++r) {
      const long row = (long)blockIdx.x * 64 + wid * 16 + qq * 4 + r;
      value[row] = pv[r] + bv0;
#pragma unroll
      for (int j = 0; j < 8; ++j) {
        adv1[row * 8 + j] = pa1[r][j] + badv1[j];
        adv2[row * 8 + j] = pa2[r][j] + badv2[j];
      }
    }
  }
}

// ---------------------------------------------------------------------------
// Kernel 4: per-batch column sums of adv1/adv2 over N (deterministic tree).
// ---------------------------------------------------------------------------
__global__ __launch_bounds__(256) void sums_kernel(const float* __restrict__ adv1,
                                                   const float* __restrict__ adv2,
                                                   float* __restrict__ sums) {
  const int b = blockIdx.x, tid = threadIdx.x;
  __shared__ float red[4][16];
  float p[16];
#pragma unroll
  for (int j = 0; j < 16; ++j) p[j] = 0.f;
  for (int n = tid; n < 2048; n += 256) {
    const long row = (long)b * 2048 + n;
    const f32x4 a1a = *(const f32x4*)(adv1 + row * 8);
    const f32x4 a1b = *(const f32x4*)(adv1 + row * 8 + 4);
    const f32x4 a2a = *(const f32x4*)(adv2 + row * 8);
    const f32x4 a2b = *(const f32x4*)(adv2 + row * 8 + 4);
#pragma unroll
    for (int j = 0; j < 4; ++j) {
      p[j] += a1a[j]; p[4 + j] += a1b[j];
      p[8 + j] += a2a[j]; p[12 + j] += a2b[j];
    }
  }
#pragma unroll
  for (int s = 1; s < 64; s <<= 1)
#pragma unroll
    for (int j = 0; j < 16; ++j) p[j] += __shfl_xor(p[j], s, 64);
  const int wid = tid >> 6;
  if ((tid & 63) == 0)
#pragma unroll
    for (int j = 0; j < 16; ++j) red[wid][j] = p[j];
  __syncthreads();
  if (tid < 16)
    sums[b * 16 + tid] = red[0][tid] + red[1][tid] + red[2][tid] + red[3][tid];
}

// ---------------------------------------------------------------------------
// Kernel 5: q1/q2 = value + adv - mean(adv). Output: [q1 | q2] fp32 flat.
// ---------------------------------------------------------------------------
__global__ void combine_kernel(const float* __restrict__ value, const float* __restrict__ adv1,
                               const float* __restrict__ adv2, const float* __restrict__ sums,
                               float* __restrict__ out) {
  const int idx = blockIdx.x * 256 + threadIdx.x;   // 0 .. 1048575
  const int half = 524288;
  const int which = (idx >= half) ? 1 : 0;
  const int rem = idx - which * half;
  const int b = rem >> 14;
  const int r2 = rem & 16383;
  const int n = r2 >> 3, j = r2 & 7;
  const long row = (long)b * 2048 + n;
  const float* adv = which ? adv2 : adv1;
  const float mean = sums[b * 16 + which * 8 + j] * (1.0f / 2048.0f);
  out[idx] = value[row] + adv[row * 8 + j] - mean;
}

// ---------------------------------------------------------------------------
extern "C" void kernel_launch(void* const* d_in, const int* in_sizes, int n_in,
                              void* d_out, int out_size, void* d_ws, size_t ws_size,
                              hipStream_t stream) {
  const float* x     = (const float*)d_in[0];
  const float* mask  = (const float*)d_in[1];
  const float* Wv    = (const float*)d_in[2];
  const float* bv    = (const float*)d_in[3];
  const float* Wk    = (const float*)d_in[4];
  const float* bk    = (const float*)d_in[5];
  const float* Wq    = (const float*)d_in[6];
  const float* bq    = (const float*)d_in[7];
  const float* Wout  = (const float*)d_in[8];
  const float* bout  = (const float*)d_in[9];
  const float* Wval  = (const float*)d_in[10];
  const float* bval  = (const float*)d_in[11];
  const float* Wadv1 = (const float*)d_in[12];
  const float* badv1 = (const float*)d_in[13];
  const float* Wadv2 = (const float*)d_in[14];
  const float* badv2 = (const float*)d_in[15];
  float* out = (float*)d_out;
  char* ws = (char*)d_ws;

  // workspace layout (bytes)
  unsigned short* q_bf   = (unsigned short*)(ws + 0);          // 16 MB
  unsigned short* Kf     = (unsigned short*)(ws + 16777216);   // 16 MB
  unsigned short* Vf     = (unsigned short*)(ws + 33554432);   // 16 MB
  unsigned short* out_at = (unsigned short*)(ws + 50331648);   // 16 MB
  float* value = (float*)(ws + 67108864);                      // 256 KB
  float* adv1  = (float*)(ws + 67371008);                      // 2 MB
  float* adv2  = (float*)(ws + 69468160);                      // 2 MB
  float* sums  = (float*)(ws + 71565312);                      // 2 KB
  unsigned short* Wf_hi = (unsigned short*)(ws + 71567360);    // 192 KB
  unsigned short* Wf_lo = (unsigned short*)(ws + 71763968);    // 192 KB
  unsigned short* WoutT = (unsigned short*)(ws + 71960576);    // 32 KB
  unsigned long long* bits = (unsigned long long*)(ws + 71993344);  // 16 MB

  prepack_kernel<<<2048, 256, 0, stream>>>(mask, bits);
  prep_kernel<<<112, 256, 0, stream>>>(Wv, Wk, Wq, Wout, Wf_hi, Wf_lo, WoutT);
  proj_kernel<<<512, 512, 0, stream>>>(x, Wf_hi, Wf_lo, bq, bk, bv, q_bf, Kf, Vf);
  attn_kernel<<<512, 256, 0, stream>>>(q_bf, Kf, Vf, bits, out_at);
  wout_heads_kernel<<<1024, 256, 0, stream>>>(out_at, WoutT, bout, Wval, bval,
                                              Wadv1, badv1, Wadv2, badv2,
                                              value, adv1, adv2);
  sums_kernel<<<32, 256, 0, stream>>>(adv1, adv2, sums);
  combine_kernel<<<4096, 256, 0, stream>>>(value, adv1, adv2, sums, out);
}